// Round 1
// baseline (3157.889 us; speedup 1.0000x reference)
//
#include <hip/hip_runtime.h>
#include <hip/hip_bf16.h>

#define B_   2
#define S_   8192
#define HID_ 768
#define NH_  12
#define HD_  64

// ---------------- fill output with bias (non-selected rows stay = bo) ------
__global__ void fill_bias_kernel(float* __restrict__ out, const float* __restrict__ bo) {
    const int total = B_ * S_ * (HID_ / 4);
    const float4* b4 = reinterpret_cast<const float4*>(bo);
    float4* o4 = reinterpret_cast<float4*>(out);
    for (int i = blockIdx.x * blockDim.x + threadIdx.x; i < total; i += gridDim.x * blockDim.x) {
        o4[i] = b4[i % (HID_ / 4)];
    }
}

// ---------------- gather selected hidden rows ------------------------------
__global__ void gather_q_kernel(const float* __restrict__ hidden, const int* __restrict__ idx,
                                float* __restrict__ Qin, int nq) {
    int m = blockIdx.x;              // 0 .. B*nq-1
    int b = m / nq, qi = m - b * nq;
    int srow = b * S_ + idx[qi];
    const float4* src = reinterpret_cast<const float4*>(hidden + (size_t)srow * HID_);
    float4* dst = reinterpret_cast<float4*>(Qin + (size_t)m * HID_);
    dst[threadIdx.x] = src[threadIdx.x];   // 192 threads * float4 = 768 floats
}

// ---------------- fp32 GEMM: C[m,n] = sum_k A[m,k]*W[n,k] + bias[n] --------
// BM=BN=128, BK=16, 256 threads, 8x8 per thread.
enum { STORE_PLAIN = 0, STORE_KV = 1, STORE_SCATTER = 2 };

template<int MODE>
__launch_bounds__(256)
__global__ void gemm128_kernel(const float* __restrict__ A, const float* __restrict__ W,
                               const float* __restrict__ bias, float* __restrict__ C,
                               int M, const int* __restrict__ idx, int nq) {
    __shared__ float As[16][132];
    __shared__ float Ws[16][132];
    const int t  = threadIdx.x;
    const int m0 = blockIdx.x * 128;
    const int n0 = blockIdx.y * 128;
    const int tm = t >> 4, tn = t & 15;

    float acc[8][8];
    #pragma unroll
    for (int i = 0; i < 8; ++i)
        #pragma unroll
        for (int j = 0; j < 8; ++j) acc[i][j] = 0.f;

    for (int k0 = 0; k0 < HID_; k0 += 16) {
        #pragma unroll
        for (int half = 0; half < 2; ++half) {
            int fid = t + half * 256;          // 0..511
            int fr = fid >> 2, fc = fid & 3;   // row 0..127, k-quad 0..3
            float4 av = make_float4(0.f, 0.f, 0.f, 0.f);
            int am = m0 + fr;
            if (am < M) av = *reinterpret_cast<const float4*>(&A[(size_t)am * HID_ + k0 + fc * 4]);
            As[fc * 4 + 0][fr] = av.x;
            As[fc * 4 + 1][fr] = av.y;
            As[fc * 4 + 2][fr] = av.z;
            As[fc * 4 + 3][fr] = av.w;
            float4 wv = *reinterpret_cast<const float4*>(&W[(size_t)(n0 + fr) * HID_ + k0 + fc * 4]);
            Ws[fc * 4 + 0][fr] = wv.x;
            Ws[fc * 4 + 1][fr] = wv.y;
            Ws[fc * 4 + 2][fr] = wv.z;
            Ws[fc * 4 + 3][fr] = wv.w;
        }
        __syncthreads();
        #pragma unroll
        for (int kk = 0; kk < 16; ++kk) {
            float4 a0 = *reinterpret_cast<const float4*>(&As[kk][tm * 8]);
            float4 a1 = *reinterpret_cast<const float4*>(&As[kk][tm * 8 + 4]);
            float4 w0 = *reinterpret_cast<const float4*>(&Ws[kk][tn * 8]);
            float4 w1 = *reinterpret_cast<const float4*>(&Ws[kk][tn * 8 + 4]);
            float a[8] = {a0.x, a0.y, a0.z, a0.w, a1.x, a1.y, a1.z, a1.w};
            float w[8] = {w0.x, w0.y, w0.z, w0.w, w1.x, w1.y, w1.z, w1.w};
            #pragma unroll
            for (int i = 0; i < 8; ++i)
                #pragma unroll
                for (int j = 0; j < 8; ++j)
                    acc[i][j] = fmaf(a[i], w[j], acc[i][j]);
        }
        __syncthreads();
    }

    float bl[8];
    #pragma unroll
    for (int j = 0; j < 8; ++j) bl[j] = bias[n0 + tn * 8 + j];

    #pragma unroll
    for (int i = 0; i < 8; ++i) {
        int m = m0 + tm * 8 + i;
        if (MODE != STORE_KV && m >= M) continue;
        float4 v0 = make_float4(acc[i][0] + bl[0], acc[i][1] + bl[1], acc[i][2] + bl[2], acc[i][3] + bl[3]);
        float4 v1 = make_float4(acc[i][4] + bl[4], acc[i][5] + bl[5], acc[i][6] + bl[6], acc[i][7] + bl[7]);
        float* p;
        if (MODE == STORE_PLAIN) {
            p = &C[(size_t)m * HID_ + n0 + tn * 8];
        } else if (MODE == STORE_KV) {
            int b = m >> 13, s = m & (S_ - 1);
            int n = n0 + tn * 8;
            int h = n >> 6, d = n & 63;
            p = &C[(((size_t)(b * NH_ + h)) * S_ + s) * HD_ + d];
        } else {
            int b = m / nq, qi = m - b * nq;
            int srow = b * S_ + idx[qi];
            p = &C[(size_t)srow * HID_ + n0 + tn * 8];
        }
        *reinterpret_cast<float4*>(p)     = v0;
        *reinterpret_cast<float4*>(p + 4) = v1;
    }
}

// ---------------- attention pass 1: raw scores + online (m,l) --------------
// block = (qtile of 64 rows, h, b), 256 threads; K-tiles of 64.
__launch_bounds__(256)
__global__ void attn_pass1_kernel(const float* __restrict__ Qsel, const float* __restrict__ Kb,
                                  float* __restrict__ scores, float2* __restrict__ ml, int nq) {
    __shared__ float qs[64][68];   // [d][row], pre-scaled by 1/8
    __shared__ float kt[64][68];   // [d][key]
    const int t  = threadIdx.x;
    const int b  = blockIdx.z, h = blockIdx.y;
    const int q0 = blockIdx.x * 64;
    const int rg = t >> 4, cg = t & 15;

    {   // stage Q (transposed, scaled)
        int r  = t >> 2;
        int d0 = (t & 3) * 16;
        int row = q0 + r;
        #pragma unroll
        for (int u = 0; u < 4; ++u) {
            float4 v = make_float4(0.f, 0.f, 0.f, 0.f);
            if (row < nq)
                v = *reinterpret_cast<const float4*>(&Qsel[(size_t)(b * nq + row) * HID_ + h * HD_ + d0 + u * 4]);
            const float sc = 0.125f;   // 1/sqrt(64)
            qs[d0 + u * 4 + 0][r] = v.x * sc;
            qs[d0 + u * 4 + 1][r] = v.y * sc;
            qs[d0 + u * 4 + 2][r] = v.z * sc;
            qs[d0 + u * 4 + 3][r] = v.w * sc;
        }
    }

    float mrow[4], lrow[4];
    #pragma unroll
    for (int i = 0; i < 4; ++i) { mrow[i] = -1e30f; lrow[i] = 0.f; }

    const size_t kbase = (size_t)(b * NH_ + h) * S_ * HD_;
    const size_t prow0 = (size_t)(b * NH_ + h) * nq;

    for (int k0 = 0; k0 < S_; k0 += 64) {
        __syncthreads();
        {   // stage K tile (transposed)
            int c  = t >> 2;
            int d0 = (t & 3) * 16;
            #pragma unroll
            for (int u = 0; u < 4; ++u) {
                float4 v = *reinterpret_cast<const float4*>(&Kb[kbase + (size_t)(k0 + c) * HD_ + d0 + u * 4]);
                kt[d0 + u * 4 + 0][c] = v.x;
                kt[d0 + u * 4 + 1][c] = v.y;
                kt[d0 + u * 4 + 2][c] = v.z;
                kt[d0 + u * 4 + 3][c] = v.w;
            }
        }
        __syncthreads();

        float acc[4][4] = {{0.f}};
        #pragma unroll
        for (int kk = 0; kk < 64; ++kk) {
            float4 qa = *reinterpret_cast<const float4*>(&qs[kk][rg * 4]);
            float4 ka = *reinterpret_cast<const float4*>(&kt[kk][cg * 4]);
            float qv[4] = {qa.x, qa.y, qa.z, qa.w};
            float kv[4] = {ka.x, ka.y, ka.z, ka.w};
            #pragma unroll
            for (int i = 0; i < 4; ++i)
                #pragma unroll
                for (int j = 0; j < 4; ++j)
                    acc[i][j] = fmaf(qv[i], kv[j], acc[i][j]);
        }

        #pragma unroll
        for (int i = 0; i < 4; ++i) {
            int row = q0 + rg * 4 + i;
            if (row < nq) {
                float4 sv = make_float4(acc[i][0], acc[i][1], acc[i][2], acc[i][3]);
                *reinterpret_cast<float4*>(&scores[(prow0 + row) * (size_t)S_ + k0 + cg * 4]) = sv;
            }
            float mloc = fmaxf(fmaxf(acc[i][0], acc[i][1]), fmaxf(acc[i][2], acc[i][3]));
            float mn   = fmaxf(mrow[i], mloc);
            float ls = __expf(acc[i][0] - mn) + __expf(acc[i][1] - mn)
                     + __expf(acc[i][2] - mn) + __expf(acc[i][3] - mn);
            lrow[i] = lrow[i] * __expf(mrow[i] - mn) + ls;
            mrow[i] = mn;
        }
    }

    #pragma unroll
    for (int i = 0; i < 4; ++i) {
        float m = mrow[i], l = lrow[i];
        #pragma unroll
        for (int off = 1; off < 16; off <<= 1) {
            float om = __shfl_xor(m, off);
            float ol = __shfl_xor(l, off);
            float mn = fmaxf(m, om);
            l = l * __expf(m - mn) + ol * __expf(om - mn);
            m = mn;
        }
        int row = q0 + rg * 4 + i;
        if (cg == 0 && row < nq) ml[prow0 + row] = make_float2(m, l);
    }
}

// ---------------- attention pass 2: probs + ctx = P*V ----------------------
__launch_bounds__(256)
__global__ void attn_pass2_kernel(const float* __restrict__ Vb, float* __restrict__ probs,
                                  const float2* __restrict__ ml, float* __restrict__ ctx, int nq) {
    __shared__ float P[64][68];    // [row][key]
    __shared__ float vt[64][68];   // [key][d]
    __shared__ float mls[64], ils[64];
    const int t  = threadIdx.x;
    const int b  = blockIdx.z, h = blockIdx.y;
    const int q0 = blockIdx.x * 64;
    const size_t vbase = (size_t)(b * NH_ + h) * S_ * HD_;
    const size_t prow0 = (size_t)(b * NH_ + h) * nq;

    if (t < 64) {
        int row = q0 + t;
        float2 v = (row < nq) ? ml[prow0 + row] : make_float2(0.f, 1.f);
        mls[t] = v.x;
        ils[t] = 1.f / v.y;
    }

    const int rr = t >> 2;
    const int c0 = (t & 3) * 16;
    const int rg = t >> 4, dg = t & 15;
    float acc[4][4] = {{0.f}};

    for (int k0 = 0; k0 < S_; k0 += 64) {
        __syncthreads();
        {   // read scores -> probs (write back) + stash in LDS
            int row = q0 + rr;
            float m = mls[rr], il = ils[rr];
            #pragma unroll
            for (int u = 0; u < 4; ++u) {
                float4 sv = make_float4(0.f, 0.f, 0.f, 0.f);
                size_t gaddr = 0;
                if (row < nq) {
                    gaddr = (prow0 + row) * (size_t)S_ + k0 + c0 + u * 4;
                    sv = *reinterpret_cast<const float4*>(&probs[gaddr]);
                }
                float4 pv;
                pv.x = __expf(sv.x - m) * il;
                pv.y = __expf(sv.y - m) * il;
                pv.z = __expf(sv.z - m) * il;
                pv.w = __expf(sv.w - m) * il;
                if (row < nq) *reinterpret_cast<float4*>(&probs[gaddr]) = pv;
                *reinterpret_cast<float4*>(&P[rr][c0 + u * 4]) = pv;
            }
        }
        {   // stage V tile (natural layout)
            int c = t >> 2;
            #pragma unroll
            for (int u = 0; u < 4; ++u) {
                float4 v = *reinterpret_cast<const float4*>(&Vb[vbase + (size_t)(k0 + c) * HD_ + c0 + u * 4]);
                *reinterpret_cast<float4*>(&vt[c][c0 + u * 4]) = v;
            }
        }
        __syncthreads();
        for (int c = 0; c < 64; ++c) {
            float4 vv = *reinterpret_cast<const float4*>(&vt[c][dg * 4]);
            #pragma unroll
            for (int i = 0; i < 4; ++i) {
                float p = P[rg * 4 + i][c];
                acc[i][0] = fmaf(p, vv.x, acc[i][0]);
                acc[i][1] = fmaf(p, vv.y, acc[i][1]);
                acc[i][2] = fmaf(p, vv.z, acc[i][2]);
                acc[i][3] = fmaf(p, vv.w, acc[i][3]);
            }
        }
    }

    #pragma unroll
    for (int i = 0; i < 4; ++i) {
        int row = q0 + rg * 4 + i;
        if (row < nq) {
            float4 v = make_float4(acc[i][0], acc[i][1], acc[i][2], acc[i][3]);
            *reinterpret_cast<float4*>(&ctx[(size_t)(b * nq + row) * HID_ + h * HD_ + dg * 4]) = v;
        }
    }
}

// ---------------------------------------------------------------------------
extern "C" void kernel_launch(void* const* d_in, const int* in_sizes, int n_in,
                              void* d_out, int out_size, void* d_ws, size_t ws_size,
                              hipStream_t stream) {
    const float* hidden = (const float*)d_in[0];
    const int*   idx    = (const int*)d_in[1];
    const float* Wq = (const float*)d_in[2];
    const float* bq = (const float*)d_in[3];
    const float* Wk = (const float*)d_in[4];
    const float* bk = (const float*)d_in[5];
    const float* Wv = (const float*)d_in[6];
    const float* bv = (const float*)d_in[7];
    const float* Wo = (const float*)d_in[8];
    const float* bo = (const float*)d_in[9];
    const int nq = in_sizes[1];

    float* out   = (float*)d_out;
    float* probs = out + (size_t)B_ * S_ * HID_;

    float* ws    = (float*)d_ws;
    float* K_buf = ws;
    float* V_buf = K_buf + (size_t)B_ * NH_ * S_ * HD_;
    float* Qin   = V_buf + (size_t)B_ * NH_ * S_ * HD_;
    float* Qsel  = Qin  + (size_t)B_ * nq * HID_;
    float* ctxb  = Qsel + (size_t)B_ * nq * HID_;
    float2* ml   = (float2*)(ctxb + (size_t)B_ * nq * HID_);

    fill_bias_kernel<<<2048, 256, 0, stream>>>(out, bo);
    gather_q_kernel<<<B_ * nq, 192, 0, stream>>>(hidden, idx, Qin, nq);

    dim3 gKV(S_ * B_ / 128, HID_ / 128);
    gemm128_kernel<STORE_KV><<<gKV, 256, 0, stream>>>(hidden, Wk, bk, K_buf, B_ * S_, nullptr, 1);
    gemm128_kernel<STORE_KV><<<gKV, 256, 0, stream>>>(hidden, Wv, bv, V_buf, B_ * S_, nullptr, 1);

    int Mq = B_ * nq;
    dim3 gQ((Mq + 127) / 128, HID_ / 128);
    gemm128_kernel<STORE_PLAIN><<<gQ, 256, 0, stream>>>(Qin, Wq, bq, Qsel, Mq, nullptr, 1);

    dim3 gA((nq + 63) / 64, NH_, B_);
    attn_pass1_kernel<<<gA, 256, 0, stream>>>(Qsel, K_buf, probs, ml, nq);
    attn_pass2_kernel<<<gA, 256, 0, stream>>>(V_buf, probs, ml, ctxb, nq);

    gemm128_kernel<STORE_SCATTER><<<gQ, 256, 0, stream>>>(ctxb, Wo, bo, out, Mq, idx, nq);
}

// Round 2
// 2560.196 us; speedup vs baseline: 1.2335x; 1.2335x over previous
//
#include <hip/hip_runtime.h>
#include <hip/hip_bf16.h>

#define B_   2
#define S_   8192
#define HID_ 768
#define NH_  12
#define HD_  64

#define KC1 512                 // keys per block, pass1
#define NC1 (S_ / KC1)          // 16 chunks
#define KC2 1024                // keys per block, pass2
#define NC2 (S_ / KC2)          // 8 chunks

// ---------------- fill output with bias (non-selected rows stay = bo) ------
__global__ void fill_bias_kernel(float* __restrict__ out, const float* __restrict__ bo) {
    const int total = B_ * S_ * (HID_ / 4);
    const float4* b4 = reinterpret_cast<const float4*>(bo);
    float4* o4 = reinterpret_cast<float4*>(out);
    for (int i = blockIdx.x * blockDim.x + threadIdx.x; i < total; i += gridDim.x * blockDim.x) {
        o4[i] = b4[i % (HID_ / 4)];
    }
}

// ---------------- gather selected hidden rows ------------------------------
__global__ void gather_q_kernel(const float* __restrict__ hidden, const int* __restrict__ idx,
                                float* __restrict__ Qin, int nq) {
    int m = blockIdx.x;              // 0 .. B*nq-1
    int b = m / nq, qi = m - b * nq;
    int srow = b * S_ + idx[qi];
    const float4* src = reinterpret_cast<const float4*>(hidden + (size_t)srow * HID_);
    float4* dst = reinterpret_cast<float4*>(Qin + (size_t)m * HID_);
    dst[threadIdx.x] = src[threadIdx.x];   // 192 threads * float4 = 768 floats
}

// ---------------- fp32 GEMM: C[m,n] = sum_k A[m,k]*W[n,k] + bias[n] --------
enum { STORE_PLAIN = 0, STORE_KV = 1, STORE_SCATTER = 2 };

template<int MODE>
__launch_bounds__(256)
__global__ void gemm128_kernel(const float* __restrict__ A, const float* __restrict__ W,
                               const float* __restrict__ bias, float* __restrict__ C,
                               int M, const int* __restrict__ idx, int nq) {
    __shared__ float As[16][132];
    __shared__ float Ws[16][132];
    const int t  = threadIdx.x;
    const int m0 = blockIdx.x * 128;
    const int n0 = blockIdx.y * 128;
    const int tm = t >> 4, tn = t & 15;

    float acc[8][8];
    #pragma unroll
    for (int i = 0; i < 8; ++i)
        #pragma unroll
        for (int j = 0; j < 8; ++j) acc[i][j] = 0.f;

    for (int k0 = 0; k0 < HID_; k0 += 16) {
        #pragma unroll
        for (int half = 0; half < 2; ++half) {
            int fid = t + half * 256;          // 0..511
            int fr = fid >> 2, fc = fid & 3;   // row 0..127, k-quad 0..3
            float4 av = make_float4(0.f, 0.f, 0.f, 0.f);
            int am = m0 + fr;
            if (am < M) av = *reinterpret_cast<const float4*>(&A[(size_t)am * HID_ + k0 + fc * 4]);
            As[fc * 4 + 0][fr] = av.x;
            As[fc * 4 + 1][fr] = av.y;
            As[fc * 4 + 2][fr] = av.z;
            As[fc * 4 + 3][fr] = av.w;
            float4 wv = *reinterpret_cast<const float4*>(&W[(size_t)(n0 + fr) * HID_ + k0 + fc * 4]);
            Ws[fc * 4 + 0][fr] = wv.x;
            Ws[fc * 4 + 1][fr] = wv.y;
            Ws[fc * 4 + 2][fr] = wv.z;
            Ws[fc * 4 + 3][fr] = wv.w;
        }
        __syncthreads();
        #pragma unroll
        for (int kk = 0; kk < 16; ++kk) {
            float4 a0 = *reinterpret_cast<const float4*>(&As[kk][tm * 8]);
            float4 a1 = *reinterpret_cast<const float4*>(&As[kk][tm * 8 + 4]);
            float4 w0 = *reinterpret_cast<const float4*>(&Ws[kk][tn * 8]);
            float4 w1 = *reinterpret_cast<const float4*>(&Ws[kk][tn * 8 + 4]);
            float a[8] = {a0.x, a0.y, a0.z, a0.w, a1.x, a1.y, a1.z, a1.w};
            float w[8] = {w0.x, w0.y, w0.z, w0.w, w1.x, w1.y, w1.z, w1.w};
            #pragma unroll
            for (int i = 0; i < 8; ++i)
                #pragma unroll
                for (int j = 0; j < 8; ++j)
                    acc[i][j] = fmaf(a[i], w[j], acc[i][j]);
        }
        __syncthreads();
    }

    float bl[8];
    #pragma unroll
    for (int j = 0; j < 8; ++j) bl[j] = bias[n0 + tn * 8 + j];

    #pragma unroll
    for (int i = 0; i < 8; ++i) {
        int m = m0 + tm * 8 + i;
        if (MODE != STORE_KV && m >= M) continue;
        float4 v0 = make_float4(acc[i][0] + bl[0], acc[i][1] + bl[1], acc[i][2] + bl[2], acc[i][3] + bl[3]);
        float4 v1 = make_float4(acc[i][4] + bl[4], acc[i][5] + bl[5], acc[i][6] + bl[6], acc[i][7] + bl[7]);
        float* p;
        if (MODE == STORE_PLAIN) {
            p = &C[(size_t)m * HID_ + n0 + tn * 8];
        } else if (MODE == STORE_KV) {
            int b = m >> 13, s = m & (S_ - 1);
            int n = n0 + tn * 8;
            int h = n >> 6, d = n & 63;
            p = &C[(((size_t)(b * NH_ + h)) * S_ + s) * HD_ + d];
        } else {
            int b = m / nq, qi = m - b * nq;
            int srow = b * S_ + idx[qi];
            p = &C[(size_t)srow * HID_ + n0 + tn * 8];
        }
        *reinterpret_cast<float4*>(p)     = v0;
        *reinterpret_cast<float4*>(p + 4) = v1;
    }
}

// ---------------- attention pass 1: raw scores + partial (m,l) per chunk ---
// grid: (qtiles, NC1, B*NH), 256 threads. Each block: 64 q-rows x 512 keys.
__launch_bounds__(256)
__global__ void attn_pass1_kernel(const float* __restrict__ Qsel, const float* __restrict__ Kb,
                                  float* __restrict__ scores, float2* __restrict__ mlp,
                                  int nq, int nqpad) {
    __shared__ float qs[64][68];   // [d][row], pre-scaled by 1/8
    __shared__ float kt[64][68];   // [d][key]
    const int t  = threadIdx.x;
    const int bh = blockIdx.z;     // b*NH + h
    const int b  = bh / NH_, h = bh - b * NH_;
    const int q0 = blockIdx.x * 64;
    const int chunk = blockIdx.y;
    const int rg = t >> 4, cg = t & 15;

    {   // stage Q (transposed, scaled)
        int r  = t >> 2;
        int d0 = (t & 3) * 16;
        int row = q0 + r;
        #pragma unroll
        for (int u = 0; u < 4; ++u) {
            float4 v = make_float4(0.f, 0.f, 0.f, 0.f);
            if (row < nq)
                v = *reinterpret_cast<const float4*>(&Qsel[(size_t)(b * nq + row) * HID_ + h * HD_ + d0 + u * 4]);
            const float sc = 0.125f;   // 1/sqrt(64)
            qs[d0 + u * 4 + 0][r] = v.x * sc;
            qs[d0 + u * 4 + 1][r] = v.y * sc;
            qs[d0 + u * 4 + 2][r] = v.z * sc;
            qs[d0 + u * 4 + 3][r] = v.w * sc;
        }
    }

    float mrow[4], lrow[4];
    #pragma unroll
    for (int i = 0; i < 4; ++i) { mrow[i] = -1e30f; lrow[i] = 0.f; }

    const size_t kbase = (size_t)bh * S_ * HD_;
    const size_t prow0 = (size_t)bh * nq;

    for (int k0 = chunk * KC1; k0 < chunk * KC1 + KC1; k0 += 64) {
        __syncthreads();
        {   // stage K tile (transposed)
            int c  = t >> 2;
            int d0 = (t & 3) * 16;
            #pragma unroll
            for (int u = 0; u < 4; ++u) {
                float4 v = *reinterpret_cast<const float4*>(&Kb[kbase + (size_t)(k0 + c) * HD_ + d0 + u * 4]);
                kt[d0 + u * 4 + 0][c] = v.x;
                kt[d0 + u * 4 + 1][c] = v.y;
                kt[d0 + u * 4 + 2][c] = v.z;
                kt[d0 + u * 4 + 3][c] = v.w;
            }
        }
        __syncthreads();

        float acc[4][4] = {{0.f}};
        #pragma unroll
        for (int kk = 0; kk < 64; ++kk) {
            float4 qa = *reinterpret_cast<const float4*>(&qs[kk][rg * 4]);
            float4 ka = *reinterpret_cast<const float4*>(&kt[kk][cg * 4]);
            float qv[4] = {qa.x, qa.y, qa.z, qa.w};
            float kv[4] = {ka.x, ka.y, ka.z, ka.w};
            #pragma unroll
            for (int i = 0; i < 4; ++i)
                #pragma unroll
                for (int j = 0; j < 4; ++j)
                    acc[i][j] = fmaf(qv[i], kv[j], acc[i][j]);
        }

        #pragma unroll
        for (int i = 0; i < 4; ++i) {
            int row = q0 + rg * 4 + i;
            if (row < nq) {
                float4 sv = make_float4(acc[i][0], acc[i][1], acc[i][2], acc[i][3]);
                *reinterpret_cast<float4*>(&scores[(prow0 + row) * (size_t)S_ + k0 + cg * 4]) = sv;
            }
            float mloc = fmaxf(fmaxf(acc[i][0], acc[i][1]), fmaxf(acc[i][2], acc[i][3]));
            float mn   = fmaxf(mrow[i], mloc);
            float ls = __expf(acc[i][0] - mn) + __expf(acc[i][1] - mn)
                     + __expf(acc[i][2] - mn) + __expf(acc[i][3] - mn);
            lrow[i] = lrow[i] * __expf(mrow[i] - mn) + ls;
            mrow[i] = mn;
        }
    }

    #pragma unroll
    for (int i = 0; i < 4; ++i) {
        float m = mrow[i], l = lrow[i];
        #pragma unroll
        for (int off = 1; off < 16; off <<= 1) {
            float om = __shfl_xor(m, off);
            float ol = __shfl_xor(l, off);
            float mn = fmaxf(m, om);
            l = l * __expf(m - mn) + ol * __expf(om - mn);
            m = mn;
        }
        int row = q0 + rg * 4 + i;
        if (cg == 0)
            mlp[((size_t)chunk * (B_ * NH_) + bh) * nqpad + row] = make_float2(m, l);
    }
}

// ---------------- combine partial (m,l) over NC1 chunks --------------------
__global__ void ml_reduce_kernel(const float2* __restrict__ mlp, float2* __restrict__ ml,
                                 int nq, int nqpad) {
    int i = blockIdx.x * blockDim.x + threadIdx.x;
    int total = B_ * NH_ * nq;
    if (i >= total) return;
    int bh = i / nq, row = i - bh * nq;
    float m = -1e30f, l = 0.f;
    #pragma unroll
    for (int c = 0; c < NC1; ++c) {
        float2 v = mlp[((size_t)c * (B_ * NH_) + bh) * nqpad + row];
        float mn = fmaxf(m, v.x);
        l = l * __expf(m - mn) + v.y * __expf(v.x - mn);
        m = mn;
    }
    ml[(size_t)bh * nq + row] = make_float2(m, l);
}

// ---------------- attention pass 2: probs + partial ctx per chunk ----------
// grid: (qtiles, NC2, B*NH), 256 threads. Each block: 64 q-rows x 1024 keys.
__launch_bounds__(256)
__global__ void attn_pass2_kernel(const float* __restrict__ Vb, float* __restrict__ probs,
                                  const float2* __restrict__ ml, float* __restrict__ ctxp, int nq) {
    __shared__ float P[64][68];    // [row][key]
    __shared__ float vt[64][68];   // [key][d]
    __shared__ float mls[64], ils[64];
    const int t  = threadIdx.x;
    const int bh = blockIdx.z;
    const int b  = bh / NH_, h = bh - b * NH_;
    const int q0 = blockIdx.x * 64;
    const int chunk = blockIdx.y;
    const size_t vbase = (size_t)bh * S_ * HD_;
    const size_t prow0 = (size_t)bh * nq;

    if (t < 64) {
        int row = q0 + t;
        float2 v = (row < nq) ? ml[prow0 + row] : make_float2(0.f, 1.f);
        mls[t] = v.x;
        ils[t] = 1.f / v.y;
    }

    const int rr = t >> 2;
    const int c0 = (t & 3) * 16;
    const int rg = t >> 4, dg = t & 15;
    float acc[4][4] = {{0.f}};

    for (int k0 = chunk * KC2; k0 < chunk * KC2 + KC2; k0 += 64) {
        __syncthreads();
        {   // read scores -> probs (write back) + stash in LDS
            int row = q0 + rr;
            float m = mls[rr], il = ils[rr];
            #pragma unroll
            for (int u = 0; u < 4; ++u) {
                float4 sv = make_float4(0.f, 0.f, 0.f, 0.f);
                size_t gaddr = 0;
                if (row < nq) {
                    gaddr = (prow0 + row) * (size_t)S_ + k0 + c0 + u * 4;
                    sv = *reinterpret_cast<const float4*>(&probs[gaddr]);
                }
                float4 pv;
                pv.x = __expf(sv.x - m) * il;
                pv.y = __expf(sv.y - m) * il;
                pv.z = __expf(sv.z - m) * il;
                pv.w = __expf(sv.w - m) * il;
                if (row < nq) *reinterpret_cast<float4*>(&probs[gaddr]) = pv;
                *reinterpret_cast<float4*>(&P[rr][c0 + u * 4]) = pv;
            }
        }
        {   // stage V tile (natural layout)
            int c = t >> 2;
            #pragma unroll
            for (int u = 0; u < 4; ++u) {
                float4 v = *reinterpret_cast<const float4*>(&Vb[vbase + (size_t)(k0 + c) * HD_ + c0 + u * 4]);
                *reinterpret_cast<float4*>(&vt[c][c0 + u * 4]) = v;
            }
        }
        __syncthreads();
        for (int c = 0; c < 64; ++c) {
            float4 vv = *reinterpret_cast<const float4*>(&vt[c][dg * 4]);
            #pragma unroll
            for (int i = 0; i < 4; ++i) {
                float p = P[rg * 4 + i][c];
                acc[i][0] = fmaf(p, vv.x, acc[i][0]);
                acc[i][1] = fmaf(p, vv.y, acc[i][1]);
                acc[i][2] = fmaf(p, vv.z, acc[i][2]);
                acc[i][3] = fmaf(p, vv.w, acc[i][3]);
            }
        }
    }

    // partial ctx for this chunk
    float* dst = ctxp + (size_t)chunk * ((size_t)B_ * nq * HID_);
    #pragma unroll
    for (int i = 0; i < 4; ++i) {
        int row = q0 + rg * 4 + i;
        if (row < nq) {
            float4 v = make_float4(acc[i][0], acc[i][1], acc[i][2], acc[i][3]);
            *reinterpret_cast<float4*>(&dst[(size_t)(b * nq + row) * HID_ + h * HD_ + dg * 4]) = v;
        }
    }
}

// ---------------- sum partial ctx over NC2 chunks --------------------------
__global__ void ctx_reduce_kernel(const float* __restrict__ ctxp, float* __restrict__ ctx, int Mq) {
    const int n4 = Mq * (HID_ / 4);
    const float4* src = reinterpret_cast<const float4*>(ctxp);
    float4* dst = reinterpret_cast<float4*>(ctx);
    for (int i = blockIdx.x * blockDim.x + threadIdx.x; i < n4; i += gridDim.x * blockDim.x) {
        float4 s = make_float4(0.f, 0.f, 0.f, 0.f);
        #pragma unroll
        for (int c = 0; c < NC2; ++c) {
            float4 v = src[(size_t)c * n4 + i];
            s.x += v.x; s.y += v.y; s.z += v.z; s.w += v.w;
        }
        dst[i] = s;
    }
}

// ---------------------------------------------------------------------------
extern "C" void kernel_launch(void* const* d_in, const int* in_sizes, int n_in,
                              void* d_out, int out_size, void* d_ws, size_t ws_size,
                              hipStream_t stream) {
    const float* hidden = (const float*)d_in[0];
    const int*   idx    = (const int*)d_in[1];
    const float* Wq = (const float*)d_in[2];
    const float* bq = (const float*)d_in[3];
    const float* Wk = (const float*)d_in[4];
    const float* bk = (const float*)d_in[5];
    const float* Wv = (const float*)d_in[6];
    const float* bv = (const float*)d_in[7];
    const float* Wo = (const float*)d_in[8];
    const float* bo = (const float*)d_in[9];
    const int nq = in_sizes[1];
    const int qtiles = (nq + 63) / 64;
    const int nqpad = qtiles * 64;
    const int Mq = B_ * nq;

    float* out   = (float*)d_out;
    float* probs = out + (size_t)B_ * S_ * HID_;

    float* ws    = (float*)d_ws;
    float* K_buf = ws;
    float* V_buf = K_buf + (size_t)B_ * NH_ * S_ * HD_;
    float* Qin   = V_buf + (size_t)B_ * NH_ * S_ * HD_;
    float* Qsel  = Qin  + (size_t)Mq * HID_;
    float* ctxb  = Qsel + (size_t)Mq * HID_;
    float* ctxp  = ctxb + (size_t)Mq * HID_;
    float2* mlp  = (float2*)(ctxp + (size_t)NC2 * Mq * HID_);
    float2* ml   = mlp + (size_t)NC1 * (B_ * NH_) * nqpad;

    fill_bias_kernel<<<2048, 256, 0, stream>>>(out, bo);
    gather_q_kernel<<<B_ * nq, 192, 0, stream>>>(hidden, idx, Qin, nq);

    dim3 gKV(S_ * B_ / 128, HID_ / 128);
    gemm128_kernel<STORE_KV><<<gKV, 256, 0, stream>>>(hidden, Wk, bk, K_buf, B_ * S_, nullptr, 1);
    gemm128_kernel<STORE_KV><<<gKV, 256, 0, stream>>>(hidden, Wv, bv, V_buf, B_ * S_, nullptr, 1);

    dim3 gQ((Mq + 127) / 128, HID_ / 128);
    gemm128_kernel<STORE_PLAIN><<<gQ, 256, 0, stream>>>(Qin, Wq, bq, Qsel, Mq, nullptr, 1);

    dim3 gA1(qtiles, NC1, B_ * NH_);
    attn_pass1_kernel<<<gA1, 256, 0, stream>>>(Qsel, K_buf, probs, mlp, nq, nqpad);

    int totalml = B_ * NH_ * nq;
    ml_reduce_kernel<<<(totalml + 255) / 256, 256, 0, stream>>>(mlp, ml, nq, nqpad);

    dim3 gA2(qtiles, NC2, B_ * NH_);
    attn_pass2_kernel<<<gA2, 256, 0, stream>>>(V_buf, probs, ml, ctxp, nq);

    ctx_reduce_kernel<<<1024, 256, 0, stream>>>(ctxp, ctxb, Mq);

    gemm128_kernel<STORE_SCATTER><<<gQ, 256, 0, stream>>>(ctxb, Wo, bo, out, Mq, idx, nq);
}

// Round 3
// 911.062 us; speedup vs baseline: 3.4662x; 2.8101x over previous
//
#include <hip/hip_runtime.h>
#include <hip/hip_bf16.h>

#define B_   2
#define S_   8192
#define HID_ 768
#define NH_  12
#define HD_  64

#define KC1 512                 // keys per block, pass1
#define NC1 (S_ / KC1)          // 16 chunks
#define KC2 1024                // keys per block, pass2
#define NC2 (S_ / KC2)          // 8 chunks

typedef __attribute__((ext_vector_type(8))) short short8;
typedef __attribute__((ext_vector_type(4))) float f32x4;

__device__ __forceinline__ ushort f2b(float x) {
    __hip_bfloat16 h = __float2bfloat16(x);
    return *reinterpret_cast<ushort*>(&h);
}

// swizzled LDS byte offset: XOR row bits into 16B-slot bits (T2 fix)
__device__ __forceinline__ int swzb(int row, int colbyte, int rowbytes) {
    return row * rowbytes + (colbyte ^ ((row & 7) << 4));
}

// ---------------- fill output with bias ------------------------------------
__global__ void fill_bias_kernel(float* __restrict__ out, const float* __restrict__ bo) {
    const int total = B_ * S_ * (HID_ / 4);
    const float4* b4 = reinterpret_cast<const float4*>(bo);
    float4* o4 = reinterpret_cast<float4*>(out);
    for (int i = blockIdx.x * blockDim.x + threadIdx.x; i < total; i += gridDim.x * blockDim.x) {
        o4[i] = b4[i % (HID_ / 4)];
    }
}

// ---------------- gather selected hidden rows ------------------------------
__global__ void gather_q_kernel(const float* __restrict__ hidden, const int* __restrict__ idx,
                                float* __restrict__ Qin, int nq) {
    int m = blockIdx.x;
    int b = m / nq, qi = m - b * nq;
    int srow = b * S_ + idx[qi];
    const float4* src = reinterpret_cast<const float4*>(hidden + (size_t)srow * HID_);
    float4* dst = reinterpret_cast<float4*>(Qin + (size_t)m * HID_);
    dst[threadIdx.x] = src[threadIdx.x];
}

// ---------------- fp32 GEMM: C[m,n] = sum_k A[m,k]*W[n,k] + bias[n] --------
enum { STORE_PLAIN = 0, STORE_KV = 1, STORE_SCATTER = 2, STORE_KV_BF16 = 3, STORE_QSEL = 4 };

template<int MODE>
__launch_bounds__(256)
__global__ void gemm128_kernel(const float* __restrict__ A, const float* __restrict__ W,
                               const float* __restrict__ bias, float* __restrict__ Cf,
                               ushort* __restrict__ Ch,
                               int M, const int* __restrict__ idx, int nq, int nqpad) {
    __shared__ float As[16][132];
    __shared__ float Ws[16][132];
    const int t  = threadIdx.x;
    const int m0 = blockIdx.x * 128;
    const int n0 = blockIdx.y * 128;
    const int tm = t >> 4, tn = t & 15;

    float acc[8][8];
    #pragma unroll
    for (int i = 0; i < 8; ++i)
        #pragma unroll
        for (int j = 0; j < 8; ++j) acc[i][j] = 0.f;

    for (int k0 = 0; k0 < HID_; k0 += 16) {
        #pragma unroll
        for (int half = 0; half < 2; ++half) {
            int fid = t + half * 256;
            int fr = fid >> 2, fc = fid & 3;
            float4 av = make_float4(0.f, 0.f, 0.f, 0.f);
            int am = m0 + fr;
            if (am < M) av = *reinterpret_cast<const float4*>(&A[(size_t)am * HID_ + k0 + fc * 4]);
            As[fc * 4 + 0][fr] = av.x;
            As[fc * 4 + 1][fr] = av.y;
            As[fc * 4 + 2][fr] = av.z;
            As[fc * 4 + 3][fr] = av.w;
            float4 wv = *reinterpret_cast<const float4*>(&W[(size_t)(n0 + fr) * HID_ + k0 + fc * 4]);
            Ws[fc * 4 + 0][fr] = wv.x;
            Ws[fc * 4 + 1][fr] = wv.y;
            Ws[fc * 4 + 2][fr] = wv.z;
            Ws[fc * 4 + 3][fr] = wv.w;
        }
        __syncthreads();
        #pragma unroll
        for (int kk = 0; kk < 16; ++kk) {
            float4 a0 = *reinterpret_cast<const float4*>(&As[kk][tm * 8]);
            float4 a1 = *reinterpret_cast<const float4*>(&As[kk][tm * 8 + 4]);
            float4 w0 = *reinterpret_cast<const float4*>(&Ws[kk][tn * 8]);
            float4 w1 = *reinterpret_cast<const float4*>(&Ws[kk][tn * 8 + 4]);
            float a[8] = {a0.x, a0.y, a0.z, a0.w, a1.x, a1.y, a1.z, a1.w};
            float w[8] = {w0.x, w0.y, w0.z, w0.w, w1.x, w1.y, w1.z, w1.w};
            #pragma unroll
            for (int i = 0; i < 8; ++i)
                #pragma unroll
                for (int j = 0; j < 8; ++j)
                    acc[i][j] = fmaf(a[i], w[j], acc[i][j]);
        }
        __syncthreads();
    }

    float bl[8];
    #pragma unroll
    for (int j = 0; j < 8; ++j) bl[j] = bias[n0 + tn * 8 + j];

    #pragma unroll
    for (int i = 0; i < 8; ++i) {
        int m = m0 + tm * 8 + i;
        if (MODE != STORE_KV && MODE != STORE_KV_BF16 && m >= M) continue;
        float v[8];
        #pragma unroll
        for (int j = 0; j < 8; ++j) v[j] = acc[i][j] + bl[j];

        if (MODE == STORE_PLAIN) {
            float* p = &Cf[(size_t)m * HID_ + n0 + tn * 8];
            *reinterpret_cast<float4*>(p)     = make_float4(v[0], v[1], v[2], v[3]);
            *reinterpret_cast<float4*>(p + 4) = make_float4(v[4], v[5], v[6], v[7]);
        } else if (MODE == STORE_SCATTER) {
            int b = m / nq, qi = m - b * nq;
            int srow = b * S_ + idx[qi];
            float* p = &Cf[(size_t)srow * HID_ + n0 + tn * 8];
            *reinterpret_cast<float4*>(p)     = make_float4(v[0], v[1], v[2], v[3]);
            *reinterpret_cast<float4*>(p + 4) = make_float4(v[4], v[5], v[6], v[7]);
        } else if (MODE == STORE_KV_BF16) {
            int b = m >> 13, s = m & (S_ - 1);
            int n = n0 + tn * 8;
            int h = n >> 6, d = n & 63;
            ushort o[8];
            #pragma unroll
            for (int j = 0; j < 8; ++j) o[j] = f2b(v[j]);
            *reinterpret_cast<uint4*>(&Ch[(((size_t)(b * NH_ + h)) * S_ + s) * HD_ + d]) =
                *reinterpret_cast<uint4*>(o);
        } else { // STORE_QSEL: bf16, pre-scaled by 1/8, padded-row layout
            int b = m / nq, qi = m - b * nq;
            ushort o[8];
            #pragma unroll
            for (int j = 0; j < 8; ++j) o[j] = f2b(v[j] * 0.125f);
            *reinterpret_cast<uint4*>(&Ch[(size_t)(b * nqpad + qi) * HID_ + n0 + tn * 8]) =
                *reinterpret_cast<uint4*>(o);
        }
    }
}

// ---------------- V transpose: [bh][s][d] -> [bh][d][s] --------------------
__global__ void transpose_v_kernel(const ushort* __restrict__ V, ushort* __restrict__ Vt) {
    __shared__ ushort tile[64][72];
    int bh = blockIdx.y;
    int k0 = blockIdx.x * 64;
    int t = threadIdx.x;
    const ushort* src = V + (size_t)bh * S_ * HD_ + (size_t)k0 * HD_;
    #pragma unroll
    for (int it = 0; it < 2; ++it) {
        int sid = t + it * 256;
        int key = sid >> 3, seg = sid & 7;
        *reinterpret_cast<uint4*>(&tile[key][seg * 8]) =
            *reinterpret_cast<const uint4*>(src + (size_t)key * HD_ + seg * 8);
    }
    __syncthreads();
    ushort* dst = Vt + (size_t)bh * HD_ * S_ + k0;
    #pragma unroll
    for (int it = 0; it < 2; ++it) {
        int sid = t + it * 256;
        int d = sid >> 3, seg = sid & 7;
        ushort tmp[8];
        #pragma unroll
        for (int j = 0; j < 8; ++j) tmp[j] = tile[seg * 8 + j][d];
        *reinterpret_cast<uint4*>(dst + (size_t)d * S_ + seg * 8) = *reinterpret_cast<uint4*>(tmp);
    }
}

// ---------------- pass1: QK^T via MFMA, partial (m,l) ----------------------
// grid (qtiles, NC1, B*NH), 256 thr = 4 waves; per block 64 q x KC1 keys.
__launch_bounds__(256, 2)
__global__ void attn_pass1_mfma(const ushort* __restrict__ Qsel, const ushort* __restrict__ Kb,
                                float2* __restrict__ mlp, int nq, int nqpad) {
    __shared__ ushort Qs[64 * 64];
    __shared__ ushort Ks[128 * 64];
    const int t = threadIdx.x;
    const int lane = t & 63, w = t >> 6;
    const int bh = blockIdx.z;
    const int b = bh / NH_, h = bh - b * NH_;
    const int q0 = blockIdx.x * 64;
    const int chunk = blockIdx.y;

    {   // stage Q tile (swizzled)
        int row = t >> 2, seg = t & 3;
        const ushort* src = Qsel + (size_t)(b * nqpad + q0 + row) * HID_ + h * HD_ + seg * 16;
        uint4 v0 = *reinterpret_cast<const uint4*>(src);
        uint4 v1 = *reinterpret_cast<const uint4*>(src + 8);
        *reinterpret_cast<uint4*>((char*)Qs + swzb(row, seg * 32, 128)) = v0;
        *reinterpret_cast<uint4*>((char*)Qs + swzb(row, seg * 32 + 16, 128)) = v1;
    }

    float m_r[4], l_r[4];
    #pragma unroll
    for (int r = 0; r < 4; ++r) { m_r[r] = -1e30f; l_r[r] = 0.f; }

    const ushort* kbase = Kb + (size_t)bh * S_ * HD_;
    short8 qa0, qa1;
    bool qload = false;

    for (int kb = 0; kb < KC1; kb += 128) {
        int k0 = chunk * KC1 + kb;
        __syncthreads();
        #pragma unroll
        for (int it = 0; it < 4; ++it) {
            int sid = t + it * 256;
            int row = sid >> 3, seg = sid & 7;
            uint4 v = *reinterpret_cast<const uint4*>(kbase + (size_t)(k0 + row) * HD_ + seg * 8);
            *reinterpret_cast<uint4*>((char*)Ks + swzb(row, seg * 16, 128)) = v;
        }
        __syncthreads();
        if (!qload) {
            qa0 = *reinterpret_cast<const short8*>((char*)Qs + swzb(16 * w + (lane & 15), (lane >> 4) * 16, 128));
            qa1 = *reinterpret_cast<const short8*>((char*)Qs + swzb(16 * w + (lane & 15), (lane >> 4) * 16 + 64, 128));
            qload = true;
        }

        f32x4 sf[8];
        #pragma unroll
        for (int ns = 0; ns < 8; ++ns) {
            short8 b0 = *reinterpret_cast<const short8*>((char*)Ks + swzb(ns * 16 + (lane & 15), (lane >> 4) * 16, 128));
            short8 b1 = *reinterpret_cast<const short8*>((char*)Ks + swzb(ns * 16 + (lane & 15), (lane >> 4) * 16 + 64, 128));
            f32x4 acc = {0.f, 0.f, 0.f, 0.f};
            acc = __builtin_amdgcn_mfma_f32_16x16x32_bf16(qa0, b0, acc, 0, 0, 0);
            acc = __builtin_amdgcn_mfma_f32_16x16x32_bf16(qa1, b1, acc, 0, 0, 0);
            sf[ns] = acc;
        }

        #pragma unroll
        for (int r = 0; r < 4; ++r) {
            float bm = sf[0][r];
            #pragma unroll
            for (int ns = 1; ns < 8; ++ns) bm = fmaxf(bm, sf[ns][r]);
            float mn = fmaxf(m_r[r], bm);
            float sum = 0.f;
            #pragma unroll
            for (int ns = 0; ns < 8; ++ns) sum += __expf(sf[ns][r] - mn);
            l_r[r] = l_r[r] * __expf(m_r[r] - mn) + sum;
            m_r[r] = mn;
        }
    }

    // reduce over the 16 col-lanes of each group
    #pragma unroll
    for (int r = 0; r < 4; ++r) {
        float m = m_r[r], l = l_r[r];
        #pragma unroll
        for (int off = 1; off < 16; off <<= 1) {
            float om = __shfl_xor(m, off);
            float ol = __shfl_xor(l, off);
            float mn = fmaxf(m, om);
            l = l * __expf(m - mn) + ol * __expf(om - mn);
            m = mn;
        }
        if ((lane & 15) == 0) {
            int row = q0 + 16 * w + 4 * (lane >> 4) + r;
            mlp[(size_t)chunk * (B_ * NH_ * nqpad) + (size_t)bh * nqpad + row] = make_float2(m, l);
        }
    }
}

// ---------------- combine partial (m,l) ------------------------------------
__global__ void ml_reduce_kernel(const float2* __restrict__ mlp, float2* __restrict__ ml, int nqpad) {
    int i = blockIdx.x * blockDim.x + threadIdx.x;
    int total = B_ * NH_ * nqpad;
    if (i >= total) return;
    float m = -1e30f, l = 0.f;
    #pragma unroll
    for (int c = 0; c < NC1; ++c) {
        float2 v = mlp[(size_t)c * total + i];
        float mn = fmaxf(m, v.x);
        l = l * __expf(m - mn) + v.y * __expf(v.x - mn);
        m = mn;
    }
    ml[i] = make_float2(m, l);
}

// ---------------- pass2: recompute QK^T, write probs, PV -> ctx partial ----
// grid (qtiles, NC2, B*NH), 256 thr = 4 waves; per block 64 q x KC2 keys.
__launch_bounds__(256, 2)
__global__ void attn_pass2_mfma(const ushort* __restrict__ Qsel, const ushort* __restrict__ Kb,
                                const ushort* __restrict__ Vtb, const float2* __restrict__ ml,
                                float* __restrict__ probs, float* __restrict__ ctxp, int nq, int nqpad) {
    __shared__ ushort Qs[64 * 64];
    __shared__ ushort Ks[128 * 64];
    __shared__ ushort Vs[64 * 128];
    __shared__ ushort Ps[64 * 128];
    __shared__ float mls[64], ils[64];
    const int t = threadIdx.x;
    const int lane = t & 63, w = t >> 6;
    const int bh = blockIdx.z;
    const int b = bh / NH_, h = bh - b * NH_;
    const int q0 = blockIdx.x * 64;
    const int chunk = blockIdx.y;

    {   // stage Q tile (swizzled)
        int row = t >> 2, seg = t & 3;
        const ushort* src = Qsel + (size_t)(b * nqpad + q0 + row) * HID_ + h * HD_ + seg * 16;
        uint4 v0 = *reinterpret_cast<const uint4*>(src);
        uint4 v1 = *reinterpret_cast<const uint4*>(src + 8);
        *reinterpret_cast<uint4*>((char*)Qs + swzb(row, seg * 32, 128)) = v0;
        *reinterpret_cast<uint4*>((char*)Qs + swzb(row, seg * 32 + 16, 128)) = v1;
    }
    if (t < 64) {
        float2 v = ml[(size_t)bh * nqpad + q0 + t];
        mls[t] = v.x;
        ils[t] = 1.f / v.y;
    }

    const ushort* kbase  = Kb  + (size_t)bh * S_ * HD_;
    const ushort* vtbase = Vtb + (size_t)bh * HD_ * S_;
    const size_t prow0 = (size_t)bh * nq;

    f32x4 accc[4];
    #pragma unroll
    for (int d = 0; d < 4; ++d) accc[d] = (f32x4){0.f, 0.f, 0.f, 0.f};

    short8 qa0, qa1;
    float mr[4], ilr[4];
    bool qload = false;

    for (int kb = 0; kb < KC2; kb += 128) {
        int k0 = chunk * KC2 + kb;
        __syncthreads();
        #pragma unroll
        for (int it = 0; it < 4; ++it) {   // K tile: 128 rows x 128B
            int sid = t + it * 256;
            int row = sid >> 3, seg = sid & 7;
            uint4 v = *reinterpret_cast<const uint4*>(kbase + (size_t)(k0 + row) * HD_ + seg * 8);
            *reinterpret_cast<uint4*>((char*)Ks + swzb(row, seg * 16, 128)) = v;
        }
        #pragma unroll
        for (int it = 0; it < 4; ++it) {   // Vt tile: 64 rows x 256B
            int sid = t + it * 256;
            int row = sid >> 4, seg = sid & 15;
            uint4 v = *reinterpret_cast<const uint4*>(vtbase + (size_t)row * S_ + k0 + seg * 8);
            *reinterpret_cast<uint4*>((char*)Vs + swzb(row, seg * 16, 256)) = v;
        }
        __syncthreads();
        if (!qload) {
            qa0 = *reinterpret_cast<const short8*>((char*)Qs + swzb(16 * w + (lane & 15), (lane >> 4) * 16, 128));
            qa1 = *reinterpret_cast<const short8*>((char*)Qs + swzb(16 * w + (lane & 15), (lane >> 4) * 16 + 64, 128));
            #pragma unroll
            for (int r = 0; r < 4; ++r) {
                int rl = 16 * w + 4 * (lane >> 4) + r;
                mr[r] = mls[rl];
                ilr[r] = ils[rl];
            }
            qload = true;
        }

        // ---- QK^T for this 128-key block; probs + P(bf16->LDS) ----
        #pragma unroll
        for (int ns = 0; ns < 8; ++ns) {
            short8 b0 = *reinterpret_cast<const short8*>((char*)Ks + swzb(ns * 16 + (lane & 15), (lane >> 4) * 16, 128));
            short8 b1 = *reinterpret_cast<const short8*>((char*)Ks + swzb(ns * 16 + (lane & 15), (lane >> 4) * 16 + 64, 128));
            f32x4 acc = {0.f, 0.f, 0.f, 0.f};
            acc = __builtin_amdgcn_mfma_f32_16x16x32_bf16(qa0, b0, acc, 0, 0, 0);
            acc = __builtin_amdgcn_mfma_f32_16x16x32_bf16(qa1, b1, acc, 0, 0, 0);
            #pragma unroll
            for (int r = 0; r < 4; ++r) {
                int rl = 16 * w + 4 * (lane >> 4) + r;
                float p = __expf(acc[r] - mr[r]) * ilr[r];
                int qrow = q0 + rl;
                if (qrow < nq)
                    probs[(prow0 + qrow) * (size_t)S_ + k0 + ns * 16 + (lane & 15)] = p;
                *reinterpret_cast<ushort*>((char*)Ps + swzb(rl, (ns * 16 + (lane & 15)) * 2, 256)) = f2b(p);
            }
        }

        // ---- PV: ctx += P * V (wave-local P region, no barrier needed) ----
        short8 pa[4];
        #pragma unroll
        for (int ks = 0; ks < 4; ++ks)
            pa[ks] = *reinterpret_cast<const short8*>((char*)Ps + swzb(16 * w + (lane & 15), ks * 64 + (lane >> 4) * 16, 256));
        #pragma unroll
        for (int ds = 0; ds < 4; ++ds) {
            #pragma unroll
            for (int ks = 0; ks < 4; ++ks) {
                short8 vb = *reinterpret_cast<const short8*>((char*)Vs + swzb(ds * 16 + (lane & 15), ks * 64 + (lane >> 4) * 16, 256));
                accc[ds] = __builtin_amdgcn_mfma_f32_16x16x32_bf16(pa[ks], vb, accc[ds], 0, 0, 0);
            }
        }
    }

    // ---- store ctx partial for this chunk ----
    float* dst = ctxp + (size_t)chunk * ((size_t)B_ * nq * HID_);
    #pragma unroll
    for (int ds = 0; ds < 4; ++ds) {
        #pragma unroll
        for (int r = 0; r < 4; ++r) {
            int qrow = q0 + 16 * w + 4 * (lane >> 4) + r;
            if (qrow < nq)
                dst[(size_t)(b * nq + qrow) * HID_ + h * HD_ + ds * 16 + (lane & 15)] = accc[ds][r];
        }
    }
}

// ---------------- sum partial ctx over NC2 chunks --------------------------
__global__ void ctx_reduce_kernel(const float* __restrict__ ctxp, float* __restrict__ ctx, int Mq) {
    const int n4 = Mq * (HID_ / 4);
    const float4* src = reinterpret_cast<const float4*>(ctxp);
    float4* dst = reinterpret_cast<float4*>(ctx);
    for (int i = blockIdx.x * blockDim.x + threadIdx.x; i < n4; i += gridDim.x * blockDim.x) {
        float4 s = make_float4(0.f, 0.f, 0.f, 0.f);
        #pragma unroll
        for (int c = 0; c < NC2; ++c) {
            float4 v = src[(size_t)c * n4 + i];
            s.x += v.x; s.y += v.y; s.z += v.z; s.w += v.w;
        }
        dst[i] = s;
    }
}

// ---------------------------------------------------------------------------
extern "C" void kernel_launch(void* const* d_in, const int* in_sizes, int n_in,
                              void* d_out, int out_size, void* d_ws, size_t ws_size,
                              hipStream_t stream) {
    const float* hidden = (const float*)d_in[0];
    const int*   idx    = (const int*)d_in[1];
    const float* Wq = (const float*)d_in[2];
    const float* bq = (const float*)d_in[3];
    const float* Wk = (const float*)d_in[4];
    const float* bk = (const float*)d_in[5];
    const float* Wv = (const float*)d_in[6];
    const float* bv = (const float*)d_in[7];
    const float* Wo = (const float*)d_in[8];
    const float* bo = (const float*)d_in[9];
    const int nq = in_sizes[1];
    const int qtiles = (nq + 63) / 64;
    const int nqpad = qtiles * 64;
    const int Mq = B_ * nq;

    float* out   = (float*)d_out;
    float* probs = out + (size_t)B_ * S_ * HID_;

    char* ws = (char*)d_ws;
    const size_t kvN = (size_t)B_ * NH_ * S_ * HD_;   // 12.58M elems
    ushort* K_buf = (ushort*)ws;                 ws += kvN * 2;
    ushort* V_buf = (ushort*)ws;                 ws += kvN * 2;
    ushort* Vt    = (ushort*)ws;                 ws += kvN * 2;
    float*  Qin   = (float*)ws;                  ws += (size_t)Mq * HID_ * 4;
    ushort* Qsel  = (ushort*)ws;                 ws += (size_t)B_ * nqpad * HID_ * 2;
    float*  ctxb  = (float*)ws;                  ws += (size_t)Mq * HID_ * 4;
    float*  ctxp  = (float*)ws;                  ws += (size_t)NC2 * Mq * HID_ * 4;
    float2* mlp   = (float2*)ws;                 ws += (size_t)NC1 * B_ * NH_ * nqpad * 8;
    float2* ml    = (float2*)ws;                 ws += (size_t)B_ * NH_ * nqpad * 8;

    fill_bias_kernel<<<2048, 256, 0, stream>>>(out, bo);
    gather_q_kernel<<<B_ * nq, 192, 0, stream>>>(hidden, idx, Qin, nq);
    hipMemsetAsync(Qsel, 0, (size_t)B_ * nqpad * HID_ * 2, stream);

    dim3 gKV(S_ * B_ / 128, HID_ / 128);
    gemm128_kernel<STORE_KV_BF16><<<gKV, 256, 0, stream>>>(hidden, Wk, bk, nullptr, K_buf, B_ * S_, nullptr, 1, 0);
    gemm128_kernel<STORE_KV_BF16><<<gKV, 256, 0, stream>>>(hidden, Wv, bv, nullptr, V_buf, B_ * S_, nullptr, 1, 0);

    transpose_v_kernel<<<dim3(S_ / 64, B_ * NH_), 256, 0, stream>>>(V_buf, Vt);

    dim3 gQ((Mq + 127) / 128, HID_ / 128);
    gemm128_kernel<STORE_QSEL><<<gQ, 256, 0, stream>>>(Qin, Wq, bq, nullptr, Qsel, Mq, nullptr, nq, nqpad);

    dim3 gA1(qtiles, NC1, B_ * NH_);
    attn_pass1_mfma<<<gA1, 256, 0, stream>>>(Qsel, K_buf, mlp, nq, nqpad);

    int totalml = B_ * NH_ * nqpad;
    ml_reduce_kernel<<<(totalml + 255) / 256, 256, 0, stream>>>(mlp, ml, nqpad);

    dim3 gA2(qtiles, NC2, B_ * NH_);
    attn_pass2_mfma<<<gA2, 256, 0, stream>>>(Qsel, K_buf, Vt, ml, probs, ctxp, nq, nqpad);

    ctx_reduce_kernel<<<1024, 256, 0, stream>>>(ctxp, ctxb, Mq);

    gemm128_kernel<STORE_SCATTER><<<gQ, 256, 0, stream>>>(ctxb, Wo, bo, out, nullptr, Mq, idx, nq, 0);
}

// Round 4
// 436.782 us; speedup vs baseline: 7.2299x; 2.0859x over previous
//
#include <hip/hip_runtime.h>
#include <hip/hip_bf16.h>

#define B_   2
#define S_   8192
#define HID_ 768
#define NH_  12
#define HD_  64

#define KC1 512                 // keys per block, pass1
#define NC1 (S_ / KC1)          // 16 chunks
#define KC2 1024                // keys per block, pass2
#define NC2 (S_ / KC2)          // 8 chunks

typedef __attribute__((ext_vector_type(8))) short short8;
typedef __attribute__((ext_vector_type(4))) float f32x4;

__device__ __forceinline__ ushort f2b(float x) {
    __hip_bfloat16 h = __float2bfloat16(x);
    return *reinterpret_cast<ushort*>(&h);
}

// swizzled LDS byte offset: XOR row bits into 16B-slot bits (T2 fix)
__device__ __forceinline__ int swzb(int row, int colbyte, int rowbytes) {
    return row * rowbytes + (colbyte ^ ((row & 7) << 4));
}

// ---------------- fill output with bias ------------------------------------
__global__ void fill_bias_kernel(float* __restrict__ out, const float* __restrict__ bo) {
    const int total = B_ * S_ * (HID_ / 4);
    const float4* b4 = reinterpret_cast<const float4*>(bo);
    float4* o4 = reinterpret_cast<float4*>(out);
    for (int i = blockIdx.x * blockDim.x + threadIdx.x; i < total; i += gridDim.x * blockDim.x) {
        o4[i] = b4[i % (HID_ / 4)];
    }
}

// ---------------- f32 -> bf16 convert (optionally scaled) ------------------
__global__ void f32_to_bf16_kernel(const float* __restrict__ in, ushort* __restrict__ out,
                                   int n4, float scale) {
    const float4* i4 = reinterpret_cast<const float4*>(in);
    ushort4* o4 = reinterpret_cast<ushort4*>(out);
    for (int i = blockIdx.x * blockDim.x + threadIdx.x; i < n4; i += gridDim.x * blockDim.x) {
        float4 v = i4[i];
        ushort4 o;
        o.x = f2b(v.x * scale);
        o.y = f2b(v.y * scale);
        o.z = f2b(v.z * scale);
        o.w = f2b(v.w * scale);
        o4[i] = o;
    }
}

// ---------------- gather selected hidden rows (bf16, padded) ---------------
__global__ void gather_qb_kernel(const ushort* __restrict__ Hb, const int* __restrict__ idx,
                                 ushort* __restrict__ Qinb, int nq, int nqpad) {
    int m = blockIdx.x;                  // 0 .. B*nqpad-1
    int b = m / nqpad, qi = m - b * nqpad;
    uint4* dst = reinterpret_cast<uint4*>(Qinb + (size_t)m * HID_);
    if (qi < nq) {
        int srow = b * S_ + idx[qi];
        const uint4* src = reinterpret_cast<const uint4*>(Hb + (size_t)srow * HID_);
        dst[threadIdx.x] = src[threadIdx.x];   // 96 threads * 8 bf16
    } else {
        dst[threadIdx.x] = make_uint4(0, 0, 0, 0);
    }
}

// ---------------- bf16 MFMA GEMM: C[m,n] = sum_k A[m,k]*W[n,k] + bias ------
// 128x128 tile, BK=64, 256 thr = 4 waves (2x2), each wave 64x64 out.
enum { GST_KV = 0, GST_PLAIN = 1 };

template<int MODE>
__launch_bounds__(256)
__global__ void gemm_bf16_kernel(const ushort* __restrict__ A, const ushort* __restrict__ W,
                                 const float* __restrict__ bias, float bscale,
                                 ushort* __restrict__ C) {
    __shared__ ushort As[128 * 64];
    __shared__ ushort Ws[128 * 64];
    const int t = threadIdx.x;
    const int lane = t & 63, w = t >> 6;
    const int wr = w >> 1, wc = w & 1;
    const int m0 = blockIdx.x * 128;
    const int n0 = blockIdx.y * 128;

    f32x4 acc[4][4];
    #pragma unroll
    for (int i = 0; i < 4; ++i)
        #pragma unroll
        for (int j = 0; j < 4; ++j) acc[i][j] = (f32x4){0.f, 0.f, 0.f, 0.f};

    for (int k0 = 0; k0 < HID_; k0 += 64) {
        __syncthreads();
        #pragma unroll
        for (int it = 0; it < 4; ++it) {
            int sid = t + it * 256;
            int row = sid >> 3, seg = sid & 7;
            uint4 va = *reinterpret_cast<const uint4*>(A + (size_t)(m0 + row) * HID_ + k0 + seg * 8);
            *reinterpret_cast<uint4*>((char*)As + swzb(row, seg * 16, 128)) = va;
            uint4 vw = *reinterpret_cast<const uint4*>(W + (size_t)(n0 + row) * HID_ + k0 + seg * 8);
            *reinterpret_cast<uint4*>((char*)Ws + swzb(row, seg * 16, 128)) = vw;
        }
        __syncthreads();

        short8 af[4][2], bf_[4][2];
        #pragma unroll
        for (int mi = 0; mi < 4; ++mi)
            #pragma unroll
            for (int kh = 0; kh < 2; ++kh)
                af[mi][kh] = *reinterpret_cast<const short8*>(
                    (char*)As + swzb(wr * 64 + mi * 16 + (lane & 15), (lane >> 4) * 16 + kh * 64, 128));
        #pragma unroll
        for (int ni = 0; ni < 4; ++ni)
            #pragma unroll
            for (int kh = 0; kh < 2; ++kh)
                bf_[ni][kh] = *reinterpret_cast<const short8*>(
                    (char*)Ws + swzb(wc * 64 + ni * 16 + (lane & 15), (lane >> 4) * 16 + kh * 64, 128));

        #pragma unroll
        for (int mi = 0; mi < 4; ++mi)
            #pragma unroll
            for (int ni = 0; ni < 4; ++ni) {
                acc[mi][ni] = __builtin_amdgcn_mfma_f32_16x16x32_bf16(af[mi][0], bf_[ni][0], acc[mi][ni], 0, 0, 0);
                acc[mi][ni] = __builtin_amdgcn_mfma_f32_16x16x32_bf16(af[mi][1], bf_[ni][1], acc[mi][ni], 0, 0, 0);
            }
    }

    float bl[4];
    #pragma unroll
    for (int ni = 0; ni < 4; ++ni)
        bl[ni] = bias[n0 + wc * 64 + ni * 16 + (lane & 15)] * bscale;

    #pragma unroll
    for (int mi = 0; mi < 4; ++mi) {
        #pragma unroll
        for (int ni = 0; ni < 4; ++ni) {
            int n = n0 + wc * 64 + ni * 16 + (lane & 15);
            #pragma unroll
            for (int r = 0; r < 4; ++r) {
                int m = m0 + wr * 64 + mi * 16 + (lane >> 4) * 4 + r;
                ushort val = f2b(acc[mi][ni][r] + bl[ni]);
                if (MODE == GST_KV) {
                    int b = m >> 13, s = m & (S_ - 1);
                    int h = n >> 6, d = n & 63;
                    C[(((size_t)(b * NH_ + h)) * S_ + s) * HD_ + d] = val;
                } else {
                    C[(size_t)m * HID_ + n] = val;
                }
            }
        }
    }
}

// ---------------- fp32 GEMM (O-projection only, scatter store) -------------
__launch_bounds__(256)
__global__ void gemm128_scatter(const float* __restrict__ A, const float* __restrict__ W,
                                const float* __restrict__ bias, float* __restrict__ Cf,
                                int M, const int* __restrict__ idx, int nq) {
    __shared__ float As[16][132];
    __shared__ float Ws[16][132];
    const int t  = threadIdx.x;
    const int m0 = blockIdx.x * 128;
    const int n0 = blockIdx.y * 128;
    const int tm = t >> 4, tn = t & 15;

    float acc[8][8];
    #pragma unroll
    for (int i = 0; i < 8; ++i)
        #pragma unroll
        for (int j = 0; j < 8; ++j) acc[i][j] = 0.f;

    for (int k0 = 0; k0 < HID_; k0 += 16) {
        #pragma unroll
        for (int half = 0; half < 2; ++half) {
            int fid = t + half * 256;
            int fr = fid >> 2, fc = fid & 3;
            float4 av = make_float4(0.f, 0.f, 0.f, 0.f);
            int am = m0 + fr;
            if (am < M) av = *reinterpret_cast<const float4*>(&A[(size_t)am * HID_ + k0 + fc * 4]);
            As[fc * 4 + 0][fr] = av.x;
            As[fc * 4 + 1][fr] = av.y;
            As[fc * 4 + 2][fr] = av.z;
            As[fc * 4 + 3][fr] = av.w;
            float4 wv = *reinterpret_cast<const float4*>(&W[(size_t)(n0 + fr) * HID_ + k0 + fc * 4]);
            Ws[fc * 4 + 0][fr] = wv.x;
            Ws[fc * 4 + 1][fr] = wv.y;
            Ws[fc * 4 + 2][fr] = wv.z;
            Ws[fc * 4 + 3][fr] = wv.w;
        }
        __syncthreads();
        #pragma unroll
        for (int kk = 0; kk < 16; ++kk) {
            float4 a0 = *reinterpret_cast<const float4*>(&As[kk][tm * 8]);
            float4 a1 = *reinterpret_cast<const float4*>(&As[kk][tm * 8 + 4]);
            float4 w0 = *reinterpret_cast<const float4*>(&Ws[kk][tn * 8]);
            float4 w1 = *reinterpret_cast<const float4*>(&Ws[kk][tn * 8 + 4]);
            float a[8] = {a0.x, a0.y, a0.z, a0.w, a1.x, a1.y, a1.z, a1.w};
            float ww[8] = {w0.x, w0.y, w0.z, w0.w, w1.x, w1.y, w1.z, w1.w};
            #pragma unroll
            for (int i = 0; i < 8; ++i)
                #pragma unroll
                for (int j = 0; j < 8; ++j)
                    acc[i][j] = fmaf(a[i], ww[j], acc[i][j]);
        }
        __syncthreads();
    }

    float bl[8];
    #pragma unroll
    for (int j = 0; j < 8; ++j) bl[j] = bias[n0 + tn * 8 + j];

    #pragma unroll
    for (int i = 0; i < 8; ++i) {
        int m = m0 + tm * 8 + i;
        if (m >= M) continue;
        int b = m / nq, qi = m - b * nq;
        int srow = b * S_ + idx[qi];
        float* p = &Cf[(size_t)srow * HID_ + n0 + tn * 8];
        *reinterpret_cast<float4*>(p)     = make_float4(acc[i][0] + bl[0], acc[i][1] + bl[1], acc[i][2] + bl[2], acc[i][3] + bl[3]);
        *reinterpret_cast<float4*>(p + 4) = make_float4(acc[i][4] + bl[4], acc[i][5] + bl[5], acc[i][6] + bl[6], acc[i][7] + bl[7]);
    }
}

// ---------------- V transpose: [bh][s][d] -> [bh][d][s] --------------------
__global__ void transpose_v_kernel(const ushort* __restrict__ V, ushort* __restrict__ Vt) {
    __shared__ ushort tile[64][72];
    int bh = blockIdx.y;
    int k0 = blockIdx.x * 64;
    int t = threadIdx.x;
    const ushort* src = V + (size_t)bh * S_ * HD_ + (size_t)k0 * HD_;
    #pragma unroll
    for (int it = 0; it < 2; ++it) {
        int sid = t + it * 256;
        int key = sid >> 3, seg = sid & 7;
        *reinterpret_cast<uint4*>(&tile[key][seg * 8]) =
            *reinterpret_cast<const uint4*>(src + (size_t)key * HD_ + seg * 8);
    }
    __syncthreads();
    ushort* dst = Vt + (size_t)bh * HD_ * S_ + k0;
    #pragma unroll
    for (int it = 0; it < 2; ++it) {
        int sid = t + it * 256;
        int d = sid >> 3, seg = sid & 7;
        ushort tmp[8];
        #pragma unroll
        for (int j = 0; j < 8; ++j) tmp[j] = tile[seg * 8 + j][d];
        *reinterpret_cast<uint4*>(dst + (size_t)d * S_ + seg * 8) = *reinterpret_cast<uint4*>(tmp);
    }
}

// ---------------- pass1: QK^T via MFMA, partial (m,l) ----------------------
__launch_bounds__(256, 2)
__global__ void attn_pass1_mfma(const ushort* __restrict__ Qsel, const ushort* __restrict__ Kb,
                                float2* __restrict__ mlp, int nq, int nqpad) {
    __shared__ ushort Qs[64 * 64];
    __shared__ ushort Ks[128 * 64];
    const int t = threadIdx.x;
    const int lane = t & 63, w = t >> 6;
    const int bh = blockIdx.z;
    const int b = bh / NH_, h = bh - b * NH_;
    const int q0 = blockIdx.x * 64;
    const int chunk = blockIdx.y;

    {   // stage Q tile (swizzled)
        int row = t >> 2, seg = t & 3;
        const ushort* src = Qsel + (size_t)(b * nqpad + q0 + row) * HID_ + h * HD_ + seg * 16;
        uint4 v0 = *reinterpret_cast<const uint4*>(src);
        uint4 v1 = *reinterpret_cast<const uint4*>(src + 8);
        *reinterpret_cast<uint4*>((char*)Qs + swzb(row, seg * 32, 128)) = v0;
        *reinterpret_cast<uint4*>((char*)Qs + swzb(row, seg * 32 + 16, 128)) = v1;
    }

    float m_r[4], l_r[4];
    #pragma unroll
    for (int r = 0; r < 4; ++r) { m_r[r] = -1e30f; l_r[r] = 0.f; }

    const ushort* kbase = Kb + (size_t)bh * S_ * HD_;
    short8 qa0, qa1;
    bool qload = false;

    for (int kb = 0; kb < KC1; kb += 128) {
        int k0 = chunk * KC1 + kb;
        __syncthreads();
        #pragma unroll
        for (int it = 0; it < 4; ++it) {
            int sid = t + it * 256;
            int row = sid >> 3, seg = sid & 7;
            uint4 v = *reinterpret_cast<const uint4*>(kbase + (size_t)(k0 + row) * HD_ + seg * 8);
            *reinterpret_cast<uint4*>((char*)Ks + swzb(row, seg * 16, 128)) = v;
        }
        __syncthreads();
        if (!qload) {
            qa0 = *reinterpret_cast<const short8*>((char*)Qs + swzb(16 * w + (lane & 15), (lane >> 4) * 16, 128));
            qa1 = *reinterpret_cast<const short8*>((char*)Qs + swzb(16 * w + (lane & 15), (lane >> 4) * 16 + 64, 128));
            qload = true;
        }

        f32x4 sf[8];
        #pragma unroll
        for (int ns = 0; ns < 8; ++ns) {
            short8 b0 = *reinterpret_cast<const short8*>((char*)Ks + swzb(ns * 16 + (lane & 15), (lane >> 4) * 16, 128));
            short8 b1 = *reinterpret_cast<const short8*>((char*)Ks + swzb(ns * 16 + (lane & 15), (lane >> 4) * 16 + 64, 128));
            f32x4 acc = {0.f, 0.f, 0.f, 0.f};
            acc = __builtin_amdgcn_mfma_f32_16x16x32_bf16(qa0, b0, acc, 0, 0, 0);
            acc = __builtin_amdgcn_mfma_f32_16x16x32_bf16(qa1, b1, acc, 0, 0, 0);
            sf[ns] = acc;
        }

        #pragma unroll
        for (int r = 0; r < 4; ++r) {
            float bm = sf[0][r];
            #pragma unroll
            for (int ns = 1; ns < 8; ++ns) bm = fmaxf(bm, sf[ns][r]);
            float mn = fmaxf(m_r[r], bm);
            float sum = 0.f;
            #pragma unroll
            for (int ns = 0; ns < 8; ++ns) sum += __expf(sf[ns][r] - mn);
            l_r[r] = l_r[r] * __expf(m_r[r] - mn) + sum;
            m_r[r] = mn;
        }
    }

    #pragma unroll
    for (int r = 0; r < 4; ++r) {
        float m = m_r[r], l = l_r[r];
        #pragma unroll
        for (int off = 1; off < 16; off <<= 1) {
            float om = __shfl_xor(m, off);
            float ol = __shfl_xor(l, off);
            float mn = fmaxf(m, om);
            l = l * __expf(m - mn) + ol * __expf(om - mn);
            m = mn;
        }
        if ((lane & 15) == 0) {
            int row = q0 + 16 * w + 4 * (lane >> 4) + r;
            mlp[(size_t)chunk * (B_ * NH_ * nqpad) + (size_t)bh * nqpad + row] = make_float2(m, l);
        }
    }
}

// ---------------- combine partial (m,l) ------------------------------------
__global__ void ml_reduce_kernel(const float2* __restrict__ mlp, float2* __restrict__ ml, int nqpad) {
    int i = blockIdx.x * blockDim.x + threadIdx.x;
    int total = B_ * NH_ * nqpad;
    if (i >= total) return;
    float m = -1e30f, l = 0.f;
    #pragma unroll
    for (int c = 0; c < NC1; ++c) {
        float2 v = mlp[(size_t)c * total + i];
        float mn = fmaxf(m, v.x);
        l = l * __expf(m - mn) + v.y * __expf(v.x - mn);
        m = mn;
    }
    ml[i] = make_float2(m, l);
}

// ---------------- pass2: recompute QK^T, write probs, PV -> ctx partial ----
__launch_bounds__(256, 2)
__global__ void attn_pass2_mfma(const ushort* __restrict__ Qsel, const ushort* __restrict__ Kb,
                                const ushort* __restrict__ Vtb, const float2* __restrict__ ml,
                                float* __restrict__ probs, float* __restrict__ ctxp, int nq, int nqpad) {
    __shared__ ushort Qs[64 * 64];
    __shared__ ushort Ks[128 * 64];
    __shared__ ushort Vs[64 * 128];
    __shared__ ushort Ps[64 * 128];
    __shared__ float mls[64], ils[64];
    const int t = threadIdx.x;
    const int lane = t & 63, w = t >> 6;
    const int bh = blockIdx.z;
    const int b = bh / NH_, h = bh - b * NH_;
    const int q0 = blockIdx.x * 64;
    const int chunk = blockIdx.y;

    {   // stage Q tile (swizzled)
        int row = t >> 2, seg = t & 3;
        const ushort* src = Qsel + (size_t)(b * nqpad + q0 + row) * HID_ + h * HD_ + seg * 16;
        uint4 v0 = *reinterpret_cast<const uint4*>(src);
        uint4 v1 = *reinterpret_cast<const uint4*>(src + 8);
        *reinterpret_cast<uint4*>((char*)Qs + swzb(row, seg * 32, 128)) = v0;
        *reinterpret_cast<uint4*>((char*)Qs + swzb(row, seg * 32 + 16, 128)) = v1;
    }
    if (t < 64) {
        float2 v = ml[(size_t)bh * nqpad + q0 + t];
        mls[t] = v.x;
        ils[t] = 1.f / v.y;
    }

    const ushort* kbase  = Kb  + (size_t)bh * S_ * HD_;
    const ushort* vtbase = Vtb + (size_t)bh * HD_ * S_;
    const size_t prow0 = (size_t)bh * nq;

    f32x4 accc[4];
    #pragma unroll
    for (int d = 0; d < 4; ++d) accc[d] = (f32x4){0.f, 0.f, 0.f, 0.f};

    short8 qa0, qa1;
    float mr[4], ilr[4];
    bool qload = false;

    for (int kb = 0; kb < KC2; kb += 128) {
        int k0 = chunk * KC2 + kb;
        __syncthreads();
        #pragma unroll
        for (int it = 0; it < 4; ++it) {   // K tile: 128 rows x 128B
            int sid = t + it * 256;
            int row = sid >> 3, seg = sid & 7;
            uint4 v = *reinterpret_cast<const uint4*>(kbase + (size_t)(k0 + row) * HD_ + seg * 8);
            *reinterpret_cast<uint4*>((char*)Ks + swzb(row, seg * 16, 128)) = v;
        }
        #pragma unroll
        for (int it = 0; it < 4; ++it) {   // Vt tile: 64 rows x 256B
            int sid = t + it * 256;
            int row = sid >> 4, seg = sid & 15;
            uint4 v = *reinterpret_cast<const uint4*>(vtbase + (size_t)row * S_ + k0 + seg * 8);
            *reinterpret_cast<uint4*>((char*)Vs + swzb(row, seg * 16, 256)) = v;
        }
        __syncthreads();
        if (!qload) {
            qa0 = *reinterpret_cast<const short8*>((char*)Qs + swzb(16 * w + (lane & 15), (lane >> 4) * 16, 128));
            qa1 = *reinterpret_cast<const short8*>((char*)Qs + swzb(16 * w + (lane & 15), (lane >> 4) * 16 + 64, 128));
            #pragma unroll
            for (int r = 0; r < 4; ++r) {
                int rl = 16 * w + 4 * (lane >> 4) + r;
                mr[r] = mls[rl];
                ilr[r] = ils[rl];
            }
            qload = true;
        }

        // ---- QK^T for this 128-key block; probs + P(bf16->LDS) ----
        #pragma unroll
        for (int ns = 0; ns < 8; ++ns) {
            short8 b0 = *reinterpret_cast<const short8*>((char*)Ks + swzb(ns * 16 + (lane & 15), (lane >> 4) * 16, 128));
            short8 b1 = *reinterpret_cast<const short8*>((char*)Ks + swzb(ns * 16 + (lane & 15), (lane >> 4) * 16 + 64, 128));
            f32x4 acc = {0.f, 0.f, 0.f, 0.f};
            acc = __builtin_amdgcn_mfma_f32_16x16x32_bf16(qa0, b0, acc, 0, 0, 0);
            acc = __builtin_amdgcn_mfma_f32_16x16x32_bf16(qa1, b1, acc, 0, 0, 0);
            #pragma unroll
            for (int r = 0; r < 4; ++r) {
                int rl = 16 * w + 4 * (lane >> 4) + r;
                float p = __expf(acc[r] - mr[r]) * ilr[r];
                int qrow = q0 + rl;
                if (qrow < nq)
                    probs[(prow0 + qrow) * (size_t)S_ + k0 + ns * 16 + (lane & 15)] = p;
                *reinterpret_cast<ushort*>((char*)Ps + swzb(rl, (ns * 16 + (lane & 15)) * 2, 256)) = f2b(p);
            }
        }

        // ---- PV: ctx += P * V (wave-local P region, no barrier needed) ----
        short8 pa[4];
        #pragma unroll
        for (int ks = 0; ks < 4; ++ks)
            pa[ks] = *reinterpret_cast<const short8*>((char*)Ps + swzb(16 * w + (lane & 15), ks * 64 + (lane >> 4) * 16, 256));
        #pragma unroll
        for (int ds = 0; ds < 4; ++ds) {
            #pragma unroll
            for (int ks = 0; ks < 4; ++ks) {
                short8 vb = *reinterpret_cast<const short8*>((char*)Vs + swzb(ds * 16 + (lane & 15), ks * 64 + (lane >> 4) * 16, 256));
                accc[ds] = __builtin_amdgcn_mfma_f32_16x16x32_bf16(pa[ks], vb, accc[ds], 0, 0, 0);
            }
        }
    }

    // ---- store ctx partial for this chunk ----
    float* dst = ctxp + (size_t)chunk * ((size_t)B_ * nq * HID_);
    #pragma unroll
    for (int ds = 0; ds < 4; ++ds) {
        #pragma unroll
        for (int r = 0; r < 4; ++r) {
            int qrow = q0 + 16 * w + 4 * (lane >> 4) + r;
            if (qrow < nq)
                dst[(size_t)(b * nq + qrow) * HID_ + h * HD_ + ds * 16 + (lane & 15)] = accc[ds][r];
        }
    }
}

// ---------------- sum partial ctx over NC2 chunks --------------------------
__global__ void ctx_reduce_kernel(const float* __restrict__ ctxp, float* __restrict__ ctx, int Mq) {
    const int n4 = Mq * (HID_ / 4);
    const float4* src = reinterpret_cast<const float4*>(ctxp);
    float4* dst = reinterpret_cast<float4*>(ctx);
    for (int i = blockIdx.x * blockDim.x + threadIdx.x; i < n4; i += gridDim.x * blockDim.x) {
        float4 s = make_float4(0.f, 0.f, 0.f, 0.f);
        #pragma unroll
        for (int c = 0; c < NC2; ++c) {
            float4 v = src[(size_t)c * n4 + i];
            s.x += v.x; s.y += v.y; s.z += v.z; s.w += v.w;
        }
        dst[i] = s;
    }
}

// ---------------------------------------------------------------------------
extern "C" void kernel_launch(void* const* d_in, const int* in_sizes, int n_in,
                              void* d_out, int out_size, void* d_ws, size_t ws_size,
                              hipStream_t stream) {
    const float* hidden = (const float*)d_in[0];
    const int*   idx    = (const int*)d_in[1];
    const float* Wq = (const float*)d_in[2];
    const float* bq = (const float*)d_in[3];
    const float* Wk = (const float*)d_in[4];
    const float* bk = (const float*)d_in[5];
    const float* Wv = (const float*)d_in[6];
    const float* bv = (const float*)d_in[7];
    const float* Wo = (const float*)d_in[8];
    const float* bo = (const float*)d_in[9];
    const int nq = in_sizes[1];
    const int qtiles = (nq + 63) / 64;
    const int nqpad = qtiles * 64;
    const int Mq = B_ * nq;
    const int Mqp = B_ * nqpad;

    float* out   = (float*)d_out;
    float* probs = out + (size_t)B_ * S_ * HID_;

    char* ws = (char*)d_ws;
    const size_t kvN = (size_t)B_ * NH_ * S_ * HD_;   // 12.58M elems
    ushort* Hb    = (ushort*)ws;                 ws += kvN * 2;
    ushort* K_buf = (ushort*)ws;                 ws += kvN * 2;
    ushort* V_buf = (ushort*)ws;                 ws += kvN * 2;
    ushort* Vt    = (ushort*)ws;                 ws += kvN * 2;
    ushort* Wkb   = (ushort*)ws;                 ws += (size_t)HID_ * HID_ * 2;
    ushort* Wvb   = (ushort*)ws;                 ws += (size_t)HID_ * HID_ * 2;
    ushort* Wqb   = (ushort*)ws;                 ws += (size_t)HID_ * HID_ * 2;
    ushort* Qinb  = (ushort*)ws;                 ws += (size_t)Mqp * HID_ * 2;
    ushort* Qsel  = (ushort*)ws;                 ws += (size_t)Mqp * HID_ * 2;
    float*  ctxb  = (float*)ws;                  ws += (size_t)Mq * HID_ * 4;
    float*  ctxp  = (float*)ws;                  ws += (size_t)NC2 * Mq * HID_ * 4;
    float2* mlp   = (float2*)ws;                 ws += (size_t)NC1 * B_ * NH_ * nqpad * 8;
    float2* ml    = (float2*)ws;                 ws += (size_t)B_ * NH_ * nqpad * 8;

    fill_bias_kernel<<<2048, 256, 0, stream>>>(out, bo);

    // conversions
    f32_to_bf16_kernel<<<2048, 256, 0, stream>>>(hidden, Hb, (int)(kvN / 4), 1.0f);
    const int wn4 = HID_ * HID_ / 4;
    f32_to_bf16_kernel<<<576, 256, 0, stream>>>(Wk, Wkb, wn4, 1.0f);
    f32_to_bf16_kernel<<<576, 256, 0, stream>>>(Wv, Wvb, wn4, 1.0f);
    f32_to_bf16_kernel<<<576, 256, 0, stream>>>(Wq, Wqb, wn4, 0.125f);   // fold 1/sqrt(HD)

    gather_qb_kernel<<<Mqp, 96, 0, stream>>>(Hb, idx, Qinb, nq, nqpad);

    // projections (bf16 MFMA)
    dim3 gKV(B_ * S_ / 128, HID_ / 128);
    gemm_bf16_kernel<GST_KV><<<gKV, 256, 0, stream>>>(Hb, Wkb, bk, 1.0f, K_buf);
    gemm_bf16_kernel<GST_KV><<<gKV, 256, 0, stream>>>(Hb, Wvb, bv, 1.0f, V_buf);

    transpose_v_kernel<<<dim3(S_ / 64, B_ * NH_), 256, 0, stream>>>(V_buf, Vt);

    dim3 gQ(Mqp / 128, HID_ / 128);
    gemm_bf16_kernel<GST_PLAIN><<<gQ, 256, 0, stream>>>(Qinb, Wqb, bq, 0.125f, Qsel);

    // attention
    dim3 gA1(qtiles, NC1, B_ * NH_);
    attn_pass1_mfma<<<gA1, 256, 0, stream>>>(Qsel, K_buf, mlp, nq, nqpad);

    int totalml = B_ * NH_ * nqpad;
    ml_reduce_kernel<<<(totalml + 255) / 256, 256, 0, stream>>>(mlp, ml, nqpad);

    dim3 gA2(qtiles, NC2, B_ * NH_);
    attn_pass2_mfma<<<gA2, 256, 0, stream>>>(Qsel, K_buf, Vt, ml, probs, ctxp, nq, nqpad);

    ctx_reduce_kernel<<<1024, 256, 0, stream>>>(ctxp, ctxb, Mq);

    // O projection kept fp32 for precision (cheap: M=Mq)
    dim3 gO((Mq + 127) / 128, HID_ / 128);
    gemm128_scatter<<<gO, 256, 0, stream>>>(ctxb, Wo, bo, out, Mq, idx, nq);
}

// Round 5
// 338.363 us; speedup vs baseline: 9.3329x; 1.2909x over previous
//
#include <hip/hip_runtime.h>
#include <hip/hip_bf16.h>

#define B_   2
#define S_   8192
#define HID_ 768
#define NH_  12
#define HD_  64

#define KC1 512                 // keys per block, pass1
#define NC1 (S_ / KC1)          // 16 chunks
#define KC2 1024                // keys per block, pass2
#define NC2 (S_ / KC2)          // 8 chunks

typedef __attribute__((ext_vector_type(8))) short short8;
typedef __attribute__((ext_vector_type(4))) float f32x4;

__device__ __forceinline__ ushort f2b(float x) {
    __hip_bfloat16 h = __float2bfloat16(x);
    return *reinterpret_cast<ushort*>(&h);
}

// swizzled LDS byte offset: XOR row bits into 16B-slot bits (T2 fix)
__device__ __forceinline__ int swzb(int row, int colbyte, int rowbytes) {
    return row * rowbytes + (colbyte ^ ((row & 7) << 4));
}

// async global->LDS 16B: linear LDS dest, caller pre-swizzles the SOURCE
__device__ __forceinline__ void glds16(const ushort* g, ushort* l) {
    __builtin_amdgcn_global_load_lds(
        (__attribute__((address_space(1))) unsigned int*)g,
        (__attribute__((address_space(3))) unsigned int*)l, 16, 0, 0);
}

// ---------------- fill output with bias ------------------------------------
__global__ void fill_bias_kernel(float* __restrict__ out, const float* __restrict__ bo) {
    const int total = B_ * S_ * (HID_ / 4);
    const float4* b4 = reinterpret_cast<const float4*>(bo);
    float4* o4 = reinterpret_cast<float4*>(out);
    for (int i = blockIdx.x * blockDim.x + threadIdx.x; i < total; i += gridDim.x * blockDim.x) {
        o4[i] = b4[i % (HID_ / 4)];
    }
}

// ---------------- f32 -> bf16 convert (optionally scaled) ------------------
__global__ void f32_to_bf16_kernel(const float* __restrict__ in, ushort* __restrict__ out,
                                   int n4, float scale) {
    const float4* i4 = reinterpret_cast<const float4*>(in);
    ushort4* o4 = reinterpret_cast<ushort4*>(out);
    for (int i = blockIdx.x * blockDim.x + threadIdx.x; i < n4; i += gridDim.x * blockDim.x) {
        float4 v = i4[i];
        ushort4 o;
        o.x = f2b(v.x * scale);
        o.y = f2b(v.y * scale);
        o.z = f2b(v.z * scale);
        o.w = f2b(v.w * scale);
        o4[i] = o;
    }
}

// ---------------- gather selected hidden rows (bf16, padded) ---------------
__global__ void gather_qb_kernel(const ushort* __restrict__ Hb, const int* __restrict__ idx,
                                 ushort* __restrict__ Qinb, int nq, int nqpad) {
    int m = blockIdx.x;                  // 0 .. B*nqpad-1
    int b = m / nqpad, qi = m - b * nqpad;
    uint4* dst = reinterpret_cast<uint4*>(Qinb + (size_t)m * HID_);
    if (qi < nq) {
        int srow = b * S_ + idx[qi];
        const uint4* src = reinterpret_cast<const uint4*>(Hb + (size_t)srow * HID_);
        dst[threadIdx.x] = src[threadIdx.x];   // 96 threads * 8 bf16
    } else {
        dst[threadIdx.x] = make_uint4(0, 0, 0, 0);
    }
}

// ---------------- bf16 MFMA GEMM: C[m,n] = sum_k A[m,k]*W[n,k] + bias ------
// 128x128 tile, BK=64, 256 thr = 4 waves (2x2), glds staging.
enum { GST_KV = 0, GST_PLAIN = 1 };

template<int MODE>
__launch_bounds__(256)
__global__ void gemm_bf16_kernel(const ushort* __restrict__ A, const ushort* __restrict__ W,
                                 const float* __restrict__ bias, float bscale,
                                 ushort* __restrict__ C) {
    __shared__ __align__(16) ushort As[128 * 64];
    __shared__ __align__(16) ushort Ws[128 * 64];
    const int t = threadIdx.x;
    const int lane = t & 63, w = t >> 6;
    const int wr = w >> 1, wc = w & 1;
    const int m0 = blockIdx.x * 128;
    const int n0 = blockIdx.y * 128;

    f32x4 acc[4][4];
    #pragma unroll
    for (int i = 0; i < 4; ++i)
        #pragma unroll
        for (int j = 0; j < 4; ++j) acc[i][j] = (f32x4){0.f, 0.f, 0.f, 0.f};

    for (int k0 = 0; k0 < HID_; k0 += 64) {
        __syncthreads();
        #pragma unroll
        for (int it = 0; it < 4; ++it) {
            int sid = t + it * 256;
            int row = sid >> 3, seg = sid & 7;
            int cb = (seg * 16) ^ ((row & 7) << 4);   // inverse-swizzled source
            glds16(A + (size_t)(m0 + row) * HID_ + k0 + cb / 2, (ushort*)((char*)As + sid * 16));
            glds16(W + (size_t)(n0 + row) * HID_ + k0 + cb / 2, (ushort*)((char*)Ws + sid * 16));
        }
        __syncthreads();

        short8 af[4][2], bf_[4][2];
        #pragma unroll
        for (int mi = 0; mi < 4; ++mi)
            #pragma unroll
            for (int kh = 0; kh < 2; ++kh)
                af[mi][kh] = *reinterpret_cast<const short8*>(
                    (char*)As + swzb(wr * 64 + mi * 16 + (lane & 15), (lane >> 4) * 16 + kh * 64, 128));
        #pragma unroll
        for (int ni = 0; ni < 4; ++ni)
            #pragma unroll
            for (int kh = 0; kh < 2; ++kh)
                bf_[ni][kh] = *reinterpret_cast<const short8*>(
                    (char*)Ws + swzb(wc * 64 + ni * 16 + (lane & 15), (lane >> 4) * 16 + kh * 64, 128));

        #pragma unroll
        for (int mi = 0; mi < 4; ++mi)
            #pragma unroll
            for (int ni = 0; ni < 4; ++ni) {
                acc[mi][ni] = __builtin_amdgcn_mfma_f32_16x16x32_bf16(af[mi][0], bf_[ni][0], acc[mi][ni], 0, 0, 0);
                acc[mi][ni] = __builtin_amdgcn_mfma_f32_16x16x32_bf16(af[mi][1], bf_[ni][1], acc[mi][ni], 0, 0, 0);
            }
    }

    float bl[4];
    #pragma unroll
    for (int ni = 0; ni < 4; ++ni)
        bl[ni] = bias[n0 + wc * 64 + ni * 16 + (lane & 15)] * bscale;

    #pragma unroll
    for (int mi = 0; mi < 4; ++mi) {
        #pragma unroll
        for (int ni = 0; ni < 4; ++ni) {
            int n = n0 + wc * 64 + ni * 16 + (lane & 15);
            #pragma unroll
            for (int r = 0; r < 4; ++r) {
                int m = m0 + wr * 64 + mi * 16 + (lane >> 4) * 4 + r;
                ushort val = f2b(acc[mi][ni][r] + bl[ni]);
                if (MODE == GST_KV) {
                    int b = m >> 13, s = m & (S_ - 1);
                    int h = n >> 6, d = n & 63;
                    C[(((size_t)(b * NH_ + h)) * S_ + s) * HD_ + d] = val;
                } else {
                    C[(size_t)m * HID_ + n] = val;
                }
            }
        }
    }
}

// ---------------- fp32 GEMM 64x64 tile (O-projection, scatter store) -------
__launch_bounds__(256)
__global__ void gemm64_scatter(const float* __restrict__ A, const float* __restrict__ W,
                               const float* __restrict__ bias, float* __restrict__ Cf,
                               int M, const int* __restrict__ idx, int nq) {
    __shared__ float As[16][68];
    __shared__ float Ws[16][68];
    const int t  = threadIdx.x;
    const int m0 = blockIdx.x * 64;
    const int n0 = blockIdx.y * 64;
    const int tm = t >> 4, tn = t & 15;

    float acc[4][4];
    #pragma unroll
    for (int i = 0; i < 4; ++i)
        #pragma unroll
        for (int j = 0; j < 4; ++j) acc[i][j] = 0.f;

    const int fr = t >> 2, fc = t & 3;
    for (int k0 = 0; k0 < HID_; k0 += 16) {
        float4 av = make_float4(0.f, 0.f, 0.f, 0.f);
        if (m0 + fr < M) av = *reinterpret_cast<const float4*>(&A[(size_t)(m0 + fr) * HID_ + k0 + fc * 4]);
        float4 wv = *reinterpret_cast<const float4*>(&W[(size_t)(n0 + fr) * HID_ + k0 + fc * 4]);
        As[fc * 4 + 0][fr] = av.x;
        As[fc * 4 + 1][fr] = av.y;
        As[fc * 4 + 2][fr] = av.z;
        As[fc * 4 + 3][fr] = av.w;
        Ws[fc * 4 + 0][fr] = wv.x;
        Ws[fc * 4 + 1][fr] = wv.y;
        Ws[fc * 4 + 2][fr] = wv.z;
        Ws[fc * 4 + 3][fr] = wv.w;
        __syncthreads();
        #pragma unroll
        for (int kk = 0; kk < 16; ++kk) {
            float4 a4 = *reinterpret_cast<const float4*>(&As[kk][tm * 4]);
            float4 w4 = *reinterpret_cast<const float4*>(&Ws[kk][tn * 4]);
            float a[4] = {a4.x, a4.y, a4.z, a4.w};
            float ww[4] = {w4.x, w4.y, w4.z, w4.w};
            #pragma unroll
            for (int i = 0; i < 4; ++i)
                #pragma unroll
                for (int j = 0; j < 4; ++j)
                    acc[i][j] = fmaf(a[i], ww[j], acc[i][j]);
        }
        __syncthreads();
    }

    float bl[4];
    #pragma unroll
    for (int j = 0; j < 4; ++j) bl[j] = bias[n0 + tn * 4 + j];

    #pragma unroll
    for (int i = 0; i < 4; ++i) {
        int m = m0 + tm * 4 + i;
        if (m >= M) continue;
        int b = m / nq, qi = m - b * nq;
        int srow = b * S_ + idx[qi];
        float* p = &Cf[(size_t)srow * HID_ + n0 + tn * 4];
        *reinterpret_cast<float4*>(p) =
            make_float4(acc[i][0] + bl[0], acc[i][1] + bl[1], acc[i][2] + bl[2], acc[i][3] + bl[3]);
    }
}

// ---------------- V transpose: [bh][s][d] -> [bh][d][s] --------------------
__global__ void transpose_v_kernel(const ushort* __restrict__ V, ushort* __restrict__ Vt) {
    __shared__ ushort tile[64][72];
    int bh = blockIdx.y;
    int k0 = blockIdx.x * 64;
    int t = threadIdx.x;
    const ushort* src = V + (size_t)bh * S_ * HD_ + (size_t)k0 * HD_;
    #pragma unroll
    for (int it = 0; it < 2; ++it) {
        int sid = t + it * 256;
        int key = sid >> 3, seg = sid & 7;
        *reinterpret_cast<uint4*>(&tile[key][seg * 8]) =
            *reinterpret_cast<const uint4*>(src + (size_t)key * HD_ + seg * 8);
    }
    __syncthreads();
    ushort* dst = Vt + (size_t)bh * HD_ * S_ + k0;
    #pragma unroll
    for (int it = 0; it < 2; ++it) {
        int sid = t + it * 256;
        int d = sid >> 3, seg = sid & 7;
        ushort tmp[8];
        #pragma unroll
        for (int j = 0; j < 8; ++j) tmp[j] = tile[seg * 8 + j][d];
        *reinterpret_cast<uint4*>(dst + (size_t)d * S_ + seg * 8) = *reinterpret_cast<uint4*>(tmp);
    }
}

// ---------------- pass1: QK^T via MFMA, partial (m,l) ----------------------
// grid (nqpad/128, NC1, B*NH), 512 thr = 8 waves, each wave 16 q-rows.
__launch_bounds__(512)
__global__ void attn_pass1_mfma(const ushort* __restrict__ Qsel, const ushort* __restrict__ Kb,
                                float2* __restrict__ mlp, int nq, int nqpad) {
    __shared__ __align__(16) ushort Ks[128 * 64];
    const int t = threadIdx.x;
    const int lane = t & 63, w = t >> 6;
    const int bh = blockIdx.z;
    const int b = bh / NH_, h = bh - b * NH_;
    const int q0 = blockIdx.x * 128;
    const int chunk = blockIdx.y;

    // Q fragments direct from global (one-time, L2-resident)
    const ushort* qp = Qsel + (size_t)(b * nqpad + q0 + 16 * w + (lane & 15)) * HID_
                       + h * HD_ + (lane >> 4) * 8;
    short8 qa0 = *reinterpret_cast<const short8*>(qp);
    short8 qa1 = *reinterpret_cast<const short8*>(qp + 32);

    float m_r[4], l_r[4];
    #pragma unroll
    for (int r = 0; r < 4; ++r) { m_r[r] = -1e30f; l_r[r] = 0.f; }

    const ushort* kbase = Kb + (size_t)bh * S_ * HD_;

    for (int kb = 0; kb < KC1; kb += 128) {
        int k0 = chunk * KC1 + kb;
        __syncthreads();
        #pragma unroll
        for (int it = 0; it < 2; ++it) {
            int sid = t + it * 512;
            int row = sid >> 3, seg = sid & 7;
            int cb = (seg * 16) ^ ((row & 7) << 4);
            glds16(kbase + (size_t)(k0 + row) * HD_ + cb / 2, (ushort*)((char*)Ks + sid * 16));
        }
        __syncthreads();

        f32x4 sf[8];
        #pragma unroll
        for (int ns = 0; ns < 8; ++ns) {
            short8 b0 = *reinterpret_cast<const short8*>((char*)Ks + swzb(ns * 16 + (lane & 15), (lane >> 4) * 16, 128));
            short8 b1 = *reinterpret_cast<const short8*>((char*)Ks + swzb(ns * 16 + (lane & 15), (lane >> 4) * 16 + 64, 128));
            f32x4 acc = {0.f, 0.f, 0.f, 0.f};
            acc = __builtin_amdgcn_mfma_f32_16x16x32_bf16(qa0, b0, acc, 0, 0, 0);
            acc = __builtin_amdgcn_mfma_f32_16x16x32_bf16(qa1, b1, acc, 0, 0, 0);
            sf[ns] = acc;
        }

        #pragma unroll
        for (int r = 0; r < 4; ++r) {
            float bm = sf[0][r];
            #pragma unroll
            for (int ns = 1; ns < 8; ++ns) bm = fmaxf(bm, sf[ns][r]);
            float mn = fmaxf(m_r[r], bm);
            float sum = 0.f;
            #pragma unroll
            for (int ns = 0; ns < 8; ++ns) sum += __expf(sf[ns][r] - mn);
            l_r[r] = l_r[r] * __expf(m_r[r] - mn) + sum;
            m_r[r] = mn;
        }
    }

    #pragma unroll
    for (int r = 0; r < 4; ++r) {
        float m = m_r[r], l = l_r[r];
        #pragma unroll
        for (int off = 1; off < 16; off <<= 1) {
            float om = __shfl_xor(m, off);
            float ol = __shfl_xor(l, off);
            float mn = fmaxf(m, om);
            l = l * __expf(m - mn) + ol * __expf(om - mn);
            m = mn;
        }
        if ((lane & 15) == 0) {
            int row = q0 + 16 * w + 4 * (lane >> 4) + r;
            mlp[(size_t)chunk * (B_ * NH_ * nqpad) + (size_t)bh * nqpad + row] = make_float2(m, l);
        }
    }
}

// ---------------- combine partial (m,l) ------------------------------------
__global__ void ml_reduce_kernel(const float2* __restrict__ mlp, float2* __restrict__ ml, int nqpad) {
    int i = blockIdx.x * blockDim.x + threadIdx.x;
    int total = B_ * NH_ * nqpad;
    if (i >= total) return;
    float m = -1e30f, l = 0.f;
    #pragma unroll
    for (int c = 0; c < NC1; ++c) {
        float2 v = mlp[(size_t)c * total + i];
        float mn = fmaxf(m, v.x);
        l = l * __expf(m - mn) + v.y * __expf(v.x - mn);
        m = mn;
    }
    ml[i] = make_float2(m, l);
}

// ---------------- pass2: recompute QK^T, write probs, PV -> ctx partial ----
// grid (nqpad/128, NC2, B*NH), 512 thr = 8 waves, each wave 16 q-rows.
__launch_bounds__(512)
__global__ void attn_pass2_mfma(const ushort* __restrict__ Qsel, const ushort* __restrict__ Kb,
                                const ushort* __restrict__ Vtb, const float2* __restrict__ ml,
                                float* __restrict__ probs, float* __restrict__ ctxp, int nq, int nqpad) {
    __shared__ __align__(16) ushort Ks[128 * 64];
    __shared__ __align__(16) ushort Vs[64 * 128];
    __shared__ __align__(16) ushort Ps[128 * 128];
    __shared__ float mls[128], ils[128];
    const int t = threadIdx.x;
    const int lane = t & 63, w = t >> 6;
    const int bh = blockIdx.z;
    const int b = bh / NH_, h = bh - b * NH_;
    const int q0 = blockIdx.x * 128;
    const int chunk = blockIdx.y;

    const ushort* qp = Qsel + (size_t)(b * nqpad + q0 + 16 * w + (lane & 15)) * HID_
                       + h * HD_ + (lane >> 4) * 8;
    short8 qa0 = *reinterpret_cast<const short8*>(qp);
    short8 qa1 = *reinterpret_cast<const short8*>(qp + 32);

    if (t < 128) {
        float2 v = ml[(size_t)bh * nqpad + q0 + t];
        mls[t] = v.x;
        ils[t] = 1.f / v.y;
    }

    const ushort* kbase  = Kb  + (size_t)bh * S_ * HD_;
    const ushort* vtbase = Vtb + (size_t)bh * HD_ * S_;
    const size_t prow0 = (size_t)bh * nq;

    f32x4 accc[4];
    #pragma unroll
    for (int d = 0; d < 4; ++d) accc[d] = (f32x4){0.f, 0.f, 0.f, 0.f};

    float mr[4], ilr[4];
    bool mload = false;

    for (int kb = 0; kb < KC2; kb += 128) {
        int k0 = chunk * KC2 + kb;
        __syncthreads();
        #pragma unroll
        for (int it = 0; it < 2; ++it) {   // K tile: 128 keys x 128B
            int sid = t + it * 512;
            int row = sid >> 3, seg = sid & 7;
            int cb = (seg * 16) ^ ((row & 7) << 4);
            glds16(kbase + (size_t)(k0 + row) * HD_ + cb / 2, (ushort*)((char*)Ks + sid * 16));
        }
        #pragma unroll
        for (int it = 0; it < 2; ++it) {   // Vt tile: 64 d-rows x 256B
            int sid = t + it * 512;
            int row = sid >> 4, seg = sid & 15;
            int cb = (seg * 16) ^ ((row & 7) << 4);
            glds16(vtbase + (size_t)row * S_ + k0 + cb / 2, (ushort*)((char*)Vs + sid * 16));
        }
        __syncthreads();
        if (!mload) {
            #pragma unroll
            for (int r = 0; r < 4; ++r) {
                int rl = 16 * w + 4 * (lane >> 4) + r;
                mr[r] = mls[rl];
                ilr[r] = ils[rl];
            }
            mload = true;
        }

        // ---- QK^T for this 128-key block; probs + P(bf16->LDS) ----
        #pragma unroll
        for (int ns = 0; ns < 8; ++ns) {
            short8 b0 = *reinterpret_cast<const short8*>((char*)Ks + swzb(ns * 16 + (lane & 15), (lane >> 4) * 16, 128));
            short8 b1 = *reinterpret_cast<const short8*>((char*)Ks + swzb(ns * 16 + (lane & 15), (lane >> 4) * 16 + 64, 128));
            f32x4 acc = {0.f, 0.f, 0.f, 0.f};
            acc = __builtin_amdgcn_mfma_f32_16x16x32_bf16(qa0, b0, acc, 0, 0, 0);
            acc = __builtin_amdgcn_mfma_f32_16x16x32_bf16(qa1, b1, acc, 0, 0, 0);
            #pragma unroll
            for (int r = 0; r < 4; ++r) {
                int rl = 16 * w + 4 * (lane >> 4) + r;
                float p = __expf(acc[r] - mr[r]) * ilr[r];
                int qrow = q0 + rl;
                if (qrow < nq)
                    probs[(prow0 + qrow) * (size_t)S_ + k0 + ns * 16 + (lane & 15)] = p;
                *reinterpret_cast<ushort*>((char*)Ps + swzb(rl, (ns * 16 + (lane & 15)) * 2, 256)) = f2b(p);
            }
        }

        // ---- PV: ctx += P * V (wave-local P region, no barrier needed) ----
        short8 pa[4];
        #pragma unroll
        for (int ks = 0; ks < 4; ++ks)
            pa[ks] = *reinterpret_cast<const short8*>((char*)Ps + swzb(16 * w + (lane & 15), ks * 64 + (lane >> 4) * 16, 256));
        #pragma unroll
        for (int ds = 0; ds < 4; ++ds) {
            #pragma unroll
            for (int ks = 0; ks < 4; ++ks) {
                short8 vb = *reinterpret_cast<const short8*>((char*)Vs + swzb(ds * 16 + (lane & 15), ks * 64 + (lane >> 4) * 16, 256));
                accc[ds] = __builtin_amdgcn_mfma_f32_16x16x32_bf16(pa[ks], vb, accc[ds], 0, 0, 0);
            }
        }
    }

    // ---- store ctx partial for this chunk ----
    float* dst = ctxp + (size_t)chunk * ((size_t)B_ * nq * HID_);
    #pragma unroll
    for (int ds = 0; ds < 4; ++ds) {
        #pragma unroll
        for (int r = 0; r < 4; ++r) {
            int qrow = q0 + 16 * w + 4 * (lane >> 4) + r;
            if (qrow < nq)
                dst[(size_t)(b * nq + qrow) * HID_ + h * HD_ + ds * 16 + (lane & 15)] = accc[ds][r];
        }
    }
}

// ---------------- sum partial ctx over NC2 chunks --------------------------
__global__ void ctx_reduce_kernel(const float* __restrict__ ctxp, float* __restrict__ ctx, int Mq) {
    const int n4 = Mq * (HID_ / 4);
    const float4* src = reinterpret_cast<const float4*>(ctxp);
    float4* dst = reinterpret_cast<float4*>(ctx);
    for (int i = blockIdx.x * blockDim.x + threadIdx.x; i < n4; i += gridDim.x * blockDim.x) {
        float4 s = make_float4(0.f, 0.f, 0.f, 0.f);
        #pragma unroll
        for (int c = 0; c < NC2; ++c) {
            float4 v = src[(size_t)c * n4 + i];
            s.x += v.x; s.y += v.y; s.z += v.z; s.w += v.w;
        }
        dst[i] = s;
    }
}

// ---------------------------------------------------------------------------
extern "C" void kernel_launch(void* const* d_in, const int* in_sizes, int n_in,
                              void* d_out, int out_size, void* d_ws, size_t ws_size,
                              hipStream_t stream) {
    const float* hidden = (const float*)d_in[0];
    const int*   idx    = (const int*)d_in[1];
    const float* Wq = (const float*)d_in[2];
    const float* bq = (const float*)d_in[3];
    const float* Wk = (const float*)d_in[4];
    const float* bk = (const float*)d_in[5];
    const float* Wv = (const float*)d_in[6];
    const float* bv = (const float*)d_in[7];
    const float* Wo = (const float*)d_in[8];
    const float* bo = (const float*)d_in[9];
    const int nq = in_sizes[1];
    const int qt128 = (nq + 127) / 128;
    const int nqpad = qt128 * 128;
    const int Mq = B_ * nq;
    const int Mqp = B_ * nqpad;

    float* out   = (float*)d_out;
    float* probs = out + (size_t)B_ * S_ * HID_;

    char* ws = (char*)d_ws;
    const size_t kvN = (size_t)B_ * NH_ * S_ * HD_;   // 12.58M elems
    ushort* Hb    = (ushort*)ws;                 ws += kvN * 2;
    ushort* K_buf = (ushort*)ws;                 ws += kvN * 2;
    ushort* V_buf = (ushort*)ws;                 ws += kvN * 2;
    ushort* Vt    = (ushort*)ws;                 ws += kvN * 2;
    ushort* Wkb   = (ushort*)ws;                 ws += (size_t)HID_ * HID_ * 2;
    ushort* Wvb   = (ushort*)ws;                 ws += (size_t)HID_ * HID_ * 2;
    ushort* Wqb   = (ushort*)ws;                 ws += (size_t)HID_ * HID_ * 2;
    ushort* Qinb  = (ushort*)ws;                 ws += (size_t)Mqp * HID_ * 2;
    ushort* Qsel  = (ushort*)ws;                 ws += (size_t)Mqp * HID_ * 2;
    float*  ctxb  = (float*)ws;                  ws += (size_t)Mq * HID_ * 4;
    float*  ctxp  = (float*)ws;                  ws += (size_t)NC2 * Mq * HID_ * 4;
    float2* mlp   = (float2*)ws;                 ws += (size_t)NC1 * B_ * NH_ * nqpad * 8;
    float2* ml    = (float2*)ws;                 ws += (size_t)B_ * NH_ * nqpad * 8;

    fill_bias_kernel<<<2048, 256, 0, stream>>>(out, bo);

    // conversions
    f32_to_bf16_kernel<<<2048, 256, 0, stream>>>(hidden, Hb, (int)(kvN / 4), 1.0f);
    const int wn4 = HID_ * HID_ / 4;
    f32_to_bf16_kernel<<<576, 256, 0, stream>>>(Wk, Wkb, wn4, 1.0f);
    f32_to_bf16_kernel<<<576, 256, 0, stream>>>(Wv, Wvb, wn4, 1.0f);
    f32_to_bf16_kernel<<<576, 256, 0, stream>>>(Wq, Wqb, wn4, 0.125f);   // fold 1/sqrt(HD)

    gather_qb_kernel<<<Mqp, 96, 0, stream>>>(Hb, idx, Qinb, nq, nqpad);

    // projections (bf16 MFMA + glds)
    dim3 gKV(B_ * S_ / 128, HID_ / 128);
    gemm_bf16_kernel<GST_KV><<<gKV, 256, 0, stream>>>(Hb, Wkb, bk, 1.0f, K_buf);
    gemm_bf16_kernel<GST_KV><<<gKV, 256, 0, stream>>>(Hb, Wvb, bv, 1.0f, V_buf);

    transpose_v_kernel<<<dim3(S_ / 64, B_ * NH_), 256, 0, stream>>>(V_buf, Vt);

    dim3 gQ(Mqp / 128, HID_ / 128);
    gemm_bf16_kernel<GST_PLAIN><<<gQ, 256, 0, stream>>>(Qinb, Wqb, bq, 0.125f, Qsel);

    // attention
    dim3 gA1(nqpad / 128, NC1, B_ * NH_);
    attn_pass1_mfma<<<gA1, 512, 0, stream>>>(Qsel, K_buf, mlp, nq, nqpad);

    int totalml = B_ * NH_ * nqpad;
    ml_reduce_kernel<<<(totalml + 255) / 256, 256, 0, stream>>>(mlp, ml, nqpad);

    dim3 gA2(nqpad / 128, NC2, B_ * NH_);
    attn_pass2_mfma<<<gA2, 512, 0, stream>>>(Qsel, K_buf, Vt, ml, probs, ctxp, nq, nqpad);

    ctx_reduce_kernel<<<1024, 256, 0, stream>>>(ctxp, ctxb, Mq);

    // O projection fp32, 64x64 tiles for parallelism (192 blocks)
    dim3 gO((Mq + 63) / 64, HID_ / 64);
    gemm64_scatter<<<gO, 256, 0, stream>>>(ctxb, Wo, bo, out, Mq, idx, nq);
}

// Round 6
// 329.443 us; speedup vs baseline: 9.5855x; 1.0271x over previous
//
#include <hip/hip_runtime.h>
#include <hip/hip_bf16.h>

#define B_   2
#define S_   8192
#define HID_ 768
#define NH_  12
#define HD_  64

#define KC1 512                 // keys per block, pass1
#define NC1 (S_ / KC1)          // 16 chunks
#define KC2 512                 // keys per block, pass2
#define NC2 (S_ / KC2)          // 16 chunks

typedef __attribute__((ext_vector_type(8))) short short8;
typedef __attribute__((ext_vector_type(4))) float f32x4;

__device__ __forceinline__ ushort f2b(float x) {
    __hip_bfloat16 h = __float2bfloat16(x);
    return *reinterpret_cast<ushort*>(&h);
}

// swizzled LDS byte offset: XOR row bits into 16B-slot bits (T2 fix)
__device__ __forceinline__ int swzb(int row, int colbyte, int rowbytes) {
    return row * rowbytes + (colbyte ^ ((row & 7) << 4));
}

// async global->LDS 16B: linear LDS dest, caller pre-swizzles the SOURCE
__device__ __forceinline__ void glds16(const ushort* g, ushort* l) {
    __builtin_amdgcn_global_load_lds(
        (__attribute__((address_space(1))) unsigned int*)g,
        (__attribute__((address_space(3))) unsigned int*)l, 16, 0, 0);
}

// ---------------- fill output with bias ------------------------------------
__global__ void fill_bias_kernel(float* __restrict__ out, const float* __restrict__ bo) {
    const int total = B_ * S_ * (HID_ / 4);
    const float4* b4 = reinterpret_cast<const float4*>(bo);
    float4* o4 = reinterpret_cast<float4*>(out);
    for (int i = blockIdx.x * blockDim.x + threadIdx.x; i < total; i += gridDim.x * blockDim.x) {
        o4[i] = b4[i % (HID_ / 4)];
    }
}

// ---------------- f32 -> bf16 convert (hidden) -----------------------------
__global__ void f32_to_bf16_kernel(const float* __restrict__ in, ushort* __restrict__ out,
                                   int n4, float scale) {
    const float4* i4 = reinterpret_cast<const float4*>(in);
    ushort4* o4 = reinterpret_cast<ushort4*>(out);
    for (int i = blockIdx.x * blockDim.x + threadIdx.x; i < n4; i += gridDim.x * blockDim.x) {
        float4 v = i4[i];
        ushort4 o;
        o.x = f2b(v.x * scale);
        o.y = f2b(v.y * scale);
        o.z = f2b(v.z * scale);
        o.w = f2b(v.w * scale);
        o4[i] = o;
    }
}

// ---------------- 4 weight matrices -> bf16 in one launch ------------------
__global__ void conv_weights_kernel(const float* __restrict__ Wk, const float* __restrict__ Wv,
                                    const float* __restrict__ Wq, const float* __restrict__ Wo,
                                    ushort* __restrict__ Wkb, ushort* __restrict__ Wvb,
                                    ushort* __restrict__ Wqb, ushort* __restrict__ Wob) {
    int which = blockIdx.y;
    const float* src = which == 0 ? Wk : (which == 1 ? Wv : (which == 2 ? Wq : Wo));
    ushort* dst = which == 0 ? Wkb : (which == 1 ? Wvb : (which == 2 ? Wqb : Wob));
    float scale = (which == 2) ? 0.125f : 1.0f;   // fold 1/sqrt(HD) into Wq
    const int n4 = HID_ * HID_ / 4;
    const float4* i4 = reinterpret_cast<const float4*>(src);
    ushort4* o4 = reinterpret_cast<ushort4*>(dst);
    for (int i = blockIdx.x * blockDim.x + threadIdx.x; i < n4; i += gridDim.x * blockDim.x) {
        float4 v = i4[i];
        ushort4 o;
        o.x = f2b(v.x * scale);
        o.y = f2b(v.y * scale);
        o.z = f2b(v.z * scale);
        o.w = f2b(v.w * scale);
        o4[i] = o;
    }
}

// ---------------- gather selected hidden rows (bf16, padded) ---------------
__global__ void gather_qb_kernel(const ushort* __restrict__ Hb, const int* __restrict__ idx,
                                 ushort* __restrict__ Qinb, int nq, int nqpad) {
    int m = blockIdx.x;                  // 0 .. B*nqpad-1
    int b = m / nqpad, qi = m - b * nqpad;
    uint4* dst = reinterpret_cast<uint4*>(Qinb + (size_t)m * HID_);
    if (qi < nq) {
        int srow = b * S_ + idx[qi];
        const uint4* src = reinterpret_cast<const uint4*>(Hb + (size_t)srow * HID_);
        dst[threadIdx.x] = src[threadIdx.x];   // 96 threads * 8 bf16
    } else {
        dst[threadIdx.x] = make_uint4(0, 0, 0, 0);
    }
}

// ---------------- bf16 MFMA GEMM: C[m,n] = sum_k A[m,k]*W[n,k] + bias ------
// 128x128 tile, BK=64, 256 thr = 4 waves (2x2), glds staging.
enum { GST_KV = 0, GST_PLAIN = 1, GST_SCATF32 = 2 };

template<int MODE>
__launch_bounds__(256)
__global__ void gemm_bf16_kernel(const ushort* __restrict__ A, const ushort* __restrict__ W,
                                 const float* __restrict__ bias, float bscale,
                                 ushort* __restrict__ C, float* __restrict__ Cf,
                                 const int* __restrict__ idx, int nq, int Mq) {
    __shared__ __align__(16) ushort As[128 * 64];
    __shared__ __align__(16) ushort Ws[128 * 64];
    const int t = threadIdx.x;
    const int lane = t & 63, w = t >> 6;
    const int wr = w >> 1, wc = w & 1;
    const int m0 = blockIdx.x * 128;
    const int n0 = blockIdx.y * 128;

    f32x4 acc[4][4];
    #pragma unroll
    for (int i = 0; i < 4; ++i)
        #pragma unroll
        for (int j = 0; j < 4; ++j) acc[i][j] = (f32x4){0.f, 0.f, 0.f, 0.f};

    for (int k0 = 0; k0 < HID_; k0 += 64) {
        __syncthreads();
        #pragma unroll
        for (int it = 0; it < 4; ++it) {
            int sid = t + it * 256;
            int row = sid >> 3, seg = sid & 7;
            int cb = (seg * 16) ^ ((row & 7) << 4);   // inverse-swizzled source
            glds16(A + (size_t)(m0 + row) * HID_ + k0 + cb / 2, (ushort*)((char*)As + sid * 16));
            glds16(W + (size_t)(n0 + row) * HID_ + k0 + cb / 2, (ushort*)((char*)Ws + sid * 16));
        }
        __syncthreads();

        short8 af[4][2], bf_[4][2];
        #pragma unroll
        for (int mi = 0; mi < 4; ++mi)
            #pragma unroll
            for (int kh = 0; kh < 2; ++kh)
                af[mi][kh] = *reinterpret_cast<const short8*>(
                    (char*)As + swzb(wr * 64 + mi * 16 + (lane & 15), (lane >> 4) * 16 + kh * 64, 128));
        #pragma unroll
        for (int ni = 0; ni < 4; ++ni)
            #pragma unroll
            for (int kh = 0; kh < 2; ++kh)
                bf_[ni][kh] = *reinterpret_cast<const short8*>(
                    (char*)Ws + swzb(wc * 64 + ni * 16 + (lane & 15), (lane >> 4) * 16 + kh * 64, 128));

        #pragma unroll
        for (int mi = 0; mi < 4; ++mi)
            #pragma unroll
            for (int ni = 0; ni < 4; ++ni) {
                acc[mi][ni] = __builtin_amdgcn_mfma_f32_16x16x32_bf16(af[mi][0], bf_[ni][0], acc[mi][ni], 0, 0, 0);
                acc[mi][ni] = __builtin_amdgcn_mfma_f32_16x16x32_bf16(af[mi][1], bf_[ni][1], acc[mi][ni], 0, 0, 0);
            }
    }

    float bl[4];
    #pragma unroll
    for (int ni = 0; ni < 4; ++ni)
        bl[ni] = bias[n0 + wc * 64 + ni * 16 + (lane & 15)] * bscale;

    #pragma unroll
    for (int mi = 0; mi < 4; ++mi) {
        #pragma unroll
        for (int ni = 0; ni < 4; ++ni) {
            int n = n0 + wc * 64 + ni * 16 + (lane & 15);
            #pragma unroll
            for (int r = 0; r < 4; ++r) {
                int m = m0 + wr * 64 + mi * 16 + (lane >> 4) * 4 + r;
                float fv = acc[mi][ni][r] + bl[ni];
                if (MODE == GST_KV) {
                    int b = m >> 13, s = m & (S_ - 1);
                    int h = n >> 6, d = n & 63;
                    C[(((size_t)(b * NH_ + h)) * S_ + s) * HD_ + d] = f2b(fv);
                } else if (MODE == GST_PLAIN) {
                    C[(size_t)m * HID_ + n] = f2b(fv);
                } else {   // GST_SCATF32: scatter fp32 rows into out
                    if (m < Mq) {
                        int b = m / nq, qi = m - b * nq;
                        int srow = b * S_ + idx[qi];
                        Cf[(size_t)srow * HID_ + n] = fv;
                    }
                }
            }
        }
    }
}

// ---------------- V transpose: [bh][s][d] -> [bh][d][s] --------------------
__global__ void transpose_v_kernel(const ushort* __restrict__ V, ushort* __restrict__ Vt) {
    __shared__ ushort tile[64][72];
    int bh = blockIdx.y;
    int k0 = blockIdx.x * 64;
    int t = threadIdx.x;
    const ushort* src = V + (size_t)bh * S_ * HD_ + (size_t)k0 * HD_;
    #pragma unroll
    for (int it = 0; it < 2; ++it) {
        int sid = t + it * 256;
        int key = sid >> 3, seg = sid & 7;
        *reinterpret_cast<uint4*>(&tile[key][seg * 8]) =
            *reinterpret_cast<const uint4*>(src + (size_t)key * HD_ + seg * 8);
    }
    __syncthreads();
    ushort* dst = Vt + (size_t)bh * HD_ * S_ + k0;
    #pragma unroll
    for (int it = 0; it < 2; ++it) {
        int sid = t + it * 256;
        int d = sid >> 3, seg = sid & 7;
        ushort tmp[8];
        #pragma unroll
        for (int j = 0; j < 8; ++j) tmp[j] = tile[seg * 8 + j][d];
        *reinterpret_cast<uint4*>(dst + (size_t)d * S_ + seg * 8) = *reinterpret_cast<uint4*>(tmp);
    }
}

// ---------------- pass1: QK^T via MFMA, partial (m,l) ----------------------
// grid (NC1, B*NH), 512 thr = 8 waves. Block stages its K chunk ONCE and
// loops all q-tiles over it (K traffic 4x lower than q-tile-in-grid).
__launch_bounds__(512)
__global__ void attn_pass1_mfma(const ushort* __restrict__ Qsel, const ushort* __restrict__ Kb,
                                float2* __restrict__ mlp, int nq, int nqpad) {
    __shared__ __align__(16) ushort Ks[128 * 64];
    const int t = threadIdx.x;
    const int lane = t & 63, w = t >> 6;
    const int chunk = blockIdx.x, bh = blockIdx.y;
    const int b = bh / NH_, h = bh - b * NH_;
    const int nqt = nqpad >> 7;           // #128-row q-tiles (<=4)

    // preload Q fragments for all q-tiles (L2-resident)
    short8 qa[4][2];
    #pragma unroll
    for (int qt = 0; qt < 4; ++qt) {
        if (qt < nqt) {
            const ushort* qp = Qsel + (size_t)(b * nqpad + qt * 128 + 16 * w + (lane & 15)) * HID_
                               + h * HD_ + (lane >> 4) * 8;
            qa[qt][0] = *reinterpret_cast<const short8*>(qp);
            qa[qt][1] = *reinterpret_cast<const short8*>(qp + 32);
        }
    }

    float m_r[4][4], l_r[4][4];
    #pragma unroll
    for (int qt = 0; qt < 4; ++qt)
        #pragma unroll
        for (int r = 0; r < 4; ++r) { m_r[qt][r] = -1e30f; l_r[qt][r] = 0.f; }

    const ushort* kbase = Kb + (size_t)bh * S_ * HD_;

    for (int kb = 0; kb < KC1; kb += 128) {
        int k0 = chunk * KC1 + kb;
        __syncthreads();
        #pragma unroll
        for (int it = 0; it < 2; ++it) {
            int sid = t + it * 512;
            int row = sid >> 3, seg = sid & 7;
            int cb = (seg * 16) ^ ((row & 7) << 4);
            glds16(kbase + (size_t)(k0 + row) * HD_ + cb / 2, (ushort*)((char*)Ks + sid * 16));
        }
        __syncthreads();

        // hoist K fragments (shared by all q-tiles)
        short8 kf[8][2];
        #pragma unroll
        for (int ns = 0; ns < 8; ++ns) {
            kf[ns][0] = *reinterpret_cast<const short8*>((char*)Ks + swzb(ns * 16 + (lane & 15), (lane >> 4) * 16, 128));
            kf[ns][1] = *reinterpret_cast<const short8*>((char*)Ks + swzb(ns * 16 + (lane & 15), (lane >> 4) * 16 + 64, 128));
        }

        #pragma unroll
        for (int qt = 0; qt < 4; ++qt) {
            if (qt >= nqt) continue;
            f32x4 sf[8];
            __builtin_amdgcn_s_setprio(1);
            #pragma unroll
            for (int ns = 0; ns < 8; ++ns) {
                f32x4 acc = {0.f, 0.f, 0.f, 0.f};
                acc = __builtin_amdgcn_mfma_f32_16x16x32_bf16(qa[qt][0], kf[ns][0], acc, 0, 0, 0);
                acc = __builtin_amdgcn_mfma_f32_16x16x32_bf16(qa[qt][1], kf[ns][1], acc, 0, 0, 0);
                sf[ns] = acc;
            }
            __builtin_amdgcn_s_setprio(0);
            #pragma unroll
            for (int r = 0; r < 4; ++r) {
                float bm = sf[0][r];
                #pragma unroll
                for (int ns = 1; ns < 8; ++ns) bm = fmaxf(bm, sf[ns][r]);
                float mn = fmaxf(m_r[qt][r], bm);
                float sum = 0.f;
                #pragma unroll
                for (int ns = 0; ns < 8; ++ns) sum += __expf(sf[ns][r] - mn);
                l_r[qt][r] = l_r[qt][r] * __expf(m_r[qt][r] - mn) + sum;
                m_r[qt][r] = mn;
            }
        }
    }

    #pragma unroll
    for (int qt = 0; qt < 4; ++qt) {
        if (qt >= nqt) continue;
        #pragma unroll
        for (int r = 0; r < 4; ++r) {
            float m = m_r[qt][r], l = l_r[qt][r];
            #pragma unroll
            for (int off = 1; off < 16; off <<= 1) {
                float om = __shfl_xor(m, off);
                float ol = __shfl_xor(l, off);
                float mn = fmaxf(m, om);
                l = l * __expf(m - mn) + ol * __expf(om - mn);
                m = mn;
            }
            if ((lane & 15) == 0) {
                int row = qt * 128 + 16 * w + 4 * (lane >> 4) + r;
                mlp[(size_t)chunk * (B_ * NH_ * nqpad) + (size_t)bh * nqpad + row] = make_float2(m, l);
            }
        }
    }
}

// ---------------- combine partial (m,l) ------------------------------------
__global__ void ml_reduce_kernel(const float2* __restrict__ mlp, float2* __restrict__ ml, int nqpad) {
    int i = blockIdx.x * blockDim.x + threadIdx.x;
    int total = B_ * NH_ * nqpad;
    if (i >= total) return;
    float m = -1e30f, l = 0.f;
    #pragma unroll
    for (int c = 0; c < NC1; ++c) {
        float2 v = mlp[(size_t)c * total + i];
        float mn = fmaxf(m, v.x);
        l = l * __expf(m - mn) + v.y * __expf(v.x - mn);
        m = mn;
    }
    ml[i] = make_float2(m, l);
}

// ---------------- pass2: recompute QK^T, write probs, PV -> ctx partial ----
// grid (NC2, B*NH), 512 thr = 8 waves. Block stages K/V chunk once, loops
// q-tiles over it.
__launch_bounds__(512)
__global__ void attn_pass2_mfma(const ushort* __restrict__ Qsel, const ushort* __restrict__ Kb,
                                const ushort* __restrict__ Vtb, const float2* __restrict__ ml,
                                float* __restrict__ probs, float* __restrict__ ctxp, int nq, int nqpad) {
    __shared__ __align__(16) ushort Ks[128 * 64];
    __shared__ __align__(16) ushort Vs[64 * 128];
    __shared__ __align__(16) ushort Ps[128 * 128];
    __shared__ float mls[512], ils[512];
    const int t = threadIdx.x;
    const int lane = t & 63, w = t >> 6;
    const int chunk = blockIdx.x, bh = blockIdx.y;
    const int b = bh / NH_, h = bh - b * NH_;
    const int nqt = nqpad >> 7;

    short8 qa[4][2];
    #pragma unroll
    for (int qt = 0; qt < 4; ++qt) {
        if (qt < nqt) {
            const ushort* qp = Qsel + (size_t)(b * nqpad + qt * 128 + 16 * w + (lane & 15)) * HID_
                               + h * HD_ + (lane >> 4) * 8;
            qa[qt][0] = *reinterpret_cast<const short8*>(qp);
            qa[qt][1] = *reinterpret_cast<const short8*>(qp + 32);
        }
    }

    if (t < nqpad) {
        float2 v = ml[(size_t)bh * nqpad + t];
        mls[t] = v.x;
        ils[t] = 1.f / v.y;
    }

    const ushort* kbase  = Kb  + (size_t)bh * S_ * HD_;
    const ushort* vtbase = Vtb + (size_t)bh * HD_ * S_;
    const size_t prow0 = (size_t)bh * nq;

    f32x4 accc[4][4];
    #pragma unroll
    for (int qt = 0; qt < 4; ++qt)
        #pragma unroll
        for (int d = 0; d < 4; ++d) accc[qt][d] = (f32x4){0.f, 0.f, 0.f, 0.f};

    for (int kb = 0; kb < KC2; kb += 128) {
        int k0 = chunk * KC2 + kb;
        __syncthreads();
        #pragma unroll
        for (int it = 0; it < 2; ++it) {   // K tile: 128 keys x 128B
            int sid = t + it * 512;
            int row = sid >> 3, seg = sid & 7;
            int cb = (seg * 16) ^ ((row & 7) << 4);
            glds16(kbase + (size_t)(k0 + row) * HD_ + cb / 2, (ushort*)((char*)Ks + sid * 16));
        }
        #pragma unroll
        for (int it = 0; it < 2; ++it) {   // Vt tile: 64 d-rows x 256B
            int sid = t + it * 512;
            int row = sid >> 4, seg = sid & 15;
            int cb = (seg * 16) ^ ((row & 7) << 4);
            glds16(vtbase + (size_t)row * S_ + k0 + cb / 2, (ushort*)((char*)Vs + sid * 16));
        }
        __syncthreads();

        #pragma unroll
        for (int qt = 0; qt < 4; ++qt) {
            if (qt >= nqt) continue;
            float mrq[4], ilq[4];
            #pragma unroll
            for (int r = 0; r < 4; ++r) {
                int row = qt * 128 + 16 * w + 4 * (lane >> 4) + r;
                mrq[r] = mls[row];
                ilq[r] = ils[row];
            }
            __builtin_amdgcn_s_setprio(1);
            #pragma unroll
            for (int ns = 0; ns < 8; ++ns) {
                short8 b0 = *reinterpret_cast<const short8*>((char*)Ks + swzb(ns * 16 + (lane & 15), (lane >> 4) * 16, 128));
                short8 b1 = *reinterpret_cast<const short8*>((char*)Ks + swzb(ns * 16 + (lane & 15), (lane >> 4) * 16 + 64, 128));
                f32x4 acc = {0.f, 0.f, 0.f, 0.f};
                acc = __builtin_amdgcn_mfma_f32_16x16x32_bf16(qa[qt][0], b0, acc, 0, 0, 0);
                acc = __builtin_amdgcn_mfma_f32_16x16x32_bf16(qa[qt][1], b1, acc, 0, 0, 0);
                #pragma unroll
                for (int r = 0; r < 4; ++r) {
                    int rl = 16 * w + 4 * (lane >> 4) + r;
                    float p = __expf(acc[r] - mrq[r]) * ilq[r];
                    int qrow = qt * 128 + rl;
                    if (qrow < nq)
                        probs[(prow0 + qrow) * (size_t)S_ + k0 + ns * 16 + (lane & 15)] = p;
                    *reinterpret_cast<ushort*>((char*)Ps + swzb(rl, (ns * 16 + (lane & 15)) * 2, 256)) = f2b(p);
                }
            }
            // PV: wave-local P slice, no barrier needed
            short8 pa[4];
            #pragma unroll
            for (int ks = 0; ks < 4; ++ks)
                pa[ks] = *reinterpret_cast<const short8*>((char*)Ps + swzb(16 * w + (lane & 15), ks * 64 + (lane >> 4) * 16, 256));
            #pragma unroll
            for (int ds = 0; ds < 4; ++ds) {
                #pragma unroll
                for (int ks = 0; ks < 4; ++ks) {
                    short8 vb = *reinterpret_cast<const short8*>((char*)Vs + swzb(ds * 16 + (lane & 15), ks * 64 + (lane >> 4) * 16, 256));
                    accc[qt][ds] = __builtin_amdgcn_mfma_f32_16x16x32_bf16(pa[ks], vb, accc[qt][ds], 0, 0, 0);
                }
            }
            __builtin_amdgcn_s_setprio(0);
        }
    }

    // store ctx partial for this chunk
    float* dst = ctxp + (size_t)chunk * ((size_t)B_ * nq * HID_);
    #pragma unroll
    for (int qt = 0; qt < 4; ++qt) {
        if (qt >= nqt) continue;
        #pragma unroll
        for (int ds = 0; ds < 4; ++ds) {
            #pragma unroll
            for (int r = 0; r < 4; ++r) {
                int qrow = qt * 128 + 16 * w + 4 * (lane >> 4) + r;
                if (qrow < nq)
                    dst[(size_t)(b * nq + qrow) * HID_ + h * HD_ + ds * 16 + (lane & 15)] = accc[qt][ds][r];
            }
        }
    }
}

// ---------------- sum partial ctx over NC2 chunks, emit bf16 ---------------
__global__ void ctx_reduce_kernel(const float* __restrict__ ctxp, ushort* __restrict__ ctxb, int Mq) {
    const int n4 = Mq * (HID_ / 4);
    const float4* src = reinterpret_cast<const float4*>(ctxp);
    ushort4* dst = reinterpret_cast<ushort4*>(ctxb);
    for (int i = blockIdx.x * blockDim.x + threadIdx.x; i < n4; i += gridDim.x * blockDim.x) {
        float4 s = make_float4(0.f, 0.f, 0.f, 0.f);
        #pragma unroll
        for (int c = 0; c < NC2; ++c) {
            float4 v = src[(size_t)c * n4 + i];
            s.x += v.x; s.y += v.y; s.z += v.z; s.w += v.w;
        }
        ushort4 o;
        o.x = f2b(s.x); o.y = f2b(s.y); o.z = f2b(s.z); o.w = f2b(s.w);
        dst[i] = o;
    }
}

// ---------------------------------------------------------------------------
extern "C" void kernel_launch(void* const* d_in, const int* in_sizes, int n_in,
                              void* d_out, int out_size, void* d_ws, size_t ws_size,
                              hipStream_t stream) {
    const float* hidden = (const float*)d_in[0];
    const int*   idx    = (const int*)d_in[1];
    const float* Wq = (const float*)d_in[2];
    const float* bq = (const float*)d_in[3];
    const float* Wk = (const float*)d_in[4];
    const float* bk = (const float*)d_in[5];
    const float* Wv = (const float*)d_in[6];
    const float* bv = (const float*)d_in[7];
    const float* Wo = (const float*)d_in[8];
    const float* bo = (const float*)d_in[9];
    const int nq = in_sizes[1];
    const int qt128 = (nq + 127) / 128;
    const int nqpad = qt128 * 128;       // <= 512 for this problem
    const int Mq = B_ * nq;
    const int Mqp = B_ * nqpad;

    float* out   = (float*)d_out;
    float* probs = out + (size_t)B_ * S_ * HID_;

    char* ws = (char*)d_ws;
    const size_t kvN = (size_t)B_ * NH_ * S_ * HD_;   // 12.58M elems
    ushort* Hb    = (ushort*)ws;                 ws += kvN * 2;
    ushort* K_buf = (ushort*)ws;                 ws += kvN * 2;
    ushort* V_buf = (ushort*)ws;                 ws += kvN * 2;
    ushort* Vt    = (ushort*)ws;                 ws += kvN * 2;
    ushort* Wkb   = (ushort*)ws;                 ws += (size_t)HID_ * HID_ * 2;
    ushort* Wvb   = (ushort*)ws;                 ws += (size_t)HID_ * HID_ * 2;
    ushort* Wqb   = (ushort*)ws;                 ws += (size_t)HID_ * HID_ * 2;
    ushort* Wob   = (ushort*)ws;                 ws += (size_t)HID_ * HID_ * 2;
    ushort* Qinb  = (ushort*)ws;                 ws += (size_t)Mqp * HID_ * 2;
    ushort* Qsel  = (ushort*)ws;                 ws += (size_t)Mqp * HID_ * 2;
    ushort* ctxb  = (ushort*)ws;                 ws += (size_t)Mqp * HID_ * 2;
    float*  ctxp  = (float*)ws;                  ws += (size_t)NC2 * Mq * HID_ * 4;
    float2* mlp   = (float2*)ws;                 ws += (size_t)NC1 * B_ * NH_ * nqpad * 8;
    float2* ml    = (float2*)ws;                 ws += (size_t)B_ * NH_ * nqpad * 8;

    fill_bias_kernel<<<2048, 256, 0, stream>>>(out, bo);

    // conversions
    f32_to_bf16_kernel<<<2048, 256, 0, stream>>>(hidden, Hb, (int)(kvN / 4), 1.0f);
    conv_weights_kernel<<<dim3(192, 4), 256, 0, stream>>>(Wk, Wv, Wq, Wo, Wkb, Wvb, Wqb, Wob);

    gather_qb_kernel<<<Mqp, 96, 0, stream>>>(Hb, idx, Qinb, nq, nqpad);

    // projections (bf16 MFMA + glds)
    dim3 gKV(B_ * S_ / 128, HID_ / 128);
    gemm_bf16_kernel<GST_KV><<<gKV, 256, 0, stream>>>(Hb, Wkb, bk, 1.0f, K_buf, nullptr, nullptr, 0, 0);
    gemm_bf16_kernel<GST_KV><<<gKV, 256, 0, stream>>>(Hb, Wvb, bv, 1.0f, V_buf, nullptr, nullptr, 0, 0);

    transpose_v_kernel<<<dim3(S_ / 64, B_ * NH_), 256, 0, stream>>>(V_buf, Vt);

    dim3 gQ(Mqp / 128, HID_ / 128);
    gemm_bf16_kernel<GST_PLAIN><<<gQ, 256, 0, stream>>>(Qinb, Wqb, bq, 0.125f, Qsel, nullptr, nullptr, 0, 0);

    // attention
    dim3 gA1(NC1, B_ * NH_);
    attn_pass1_mfma<<<gA1, 512, 0, stream>>>(Qsel, K_buf, mlp, nq, nqpad);

    int totalml = B_ * NH_ * nqpad;
    ml_reduce_kernel<<<(totalml + 255) / 256, 256, 0, stream>>>(mlp, ml, nqpad);

    dim3 gA2(NC2, B_ * NH_);
    attn_pass2_mfma<<<gA2, 512, 0, stream>>>(Qsel, K_buf, Vt, ml, probs, ctxp, nq, nqpad);

    ctx_reduce_kernel<<<1024, 256, 0, stream>>>(ctxp, ctxb, Mq);

    // O projection: bf16 MFMA, scatter fp32 rows into out
    dim3 gO(Mqp / 128, HID_ / 128);
    gemm_bf16_kernel<GST_SCATF32><<<gO, 256, 0, stream>>>(ctxb, Wob, bo, 1.0f, nullptr, out, idx, nq, Mq);
}

// Round 7
// 299.869 us; speedup vs baseline: 10.5309x; 1.0986x over previous
//
#include <hip/hip_runtime.h>
#include <hip/hip_bf16.h>

#define B_   2
#define S_   8192
#define HID_ 768
#define NH_  12
#define HD_  64

#define KC1 256                 // keys per block, pass1
#define NC1 (S_ / KC1)          // 32 chunks
#define KC2 512                 // keys per block, pass2
#define NC2 (S_ / KC2)          // 16 chunks

typedef __attribute__((ext_vector_type(8))) short short8;
typedef __attribute__((ext_vector_type(4))) float f32x4;

__device__ __forceinline__ ushort f2b(float x) {
    __hip_bfloat16 h = __float2bfloat16(x);
    return *reinterpret_cast<ushort*>(&h);
}

// swizzled LDS byte offset: XOR row bits into 16B-slot bits (T2 fix)
__device__ __forceinline__ int swzb(int row, int colbyte, int rowbytes) {
    return row * rowbytes + (colbyte ^ ((row & 7) << 4));
}

// async global->LDS 16B: linear LDS dest, caller pre-swizzles the SOURCE
__device__ __forceinline__ void glds16(const ushort* g, ushort* l) {
    __builtin_amdgcn_global_load_lds(
        (__attribute__((address_space(1))) unsigned int*)g,
        (__attribute__((address_space(3))) unsigned int*)l, 16, 0, 0);
}

// ---------------- prep: hidden->bf16, out bias-fill, 4 weights->bf16 -------
#define N4H (B_ * S_ * HID_ / 4)
#define N4W (HID_ * HID_ / 4)
__global__ void prep_kernel(const float* __restrict__ hidden, const float* __restrict__ bo,
                            const float* __restrict__ Wk, const float* __restrict__ Wv,
                            const float* __restrict__ Wq, const float* __restrict__ Wo,
                            ushort* __restrict__ Hb, float* __restrict__ out,
                            ushort* __restrict__ Wkb, ushort* __restrict__ Wvb,
                            ushort* __restrict__ Wqb, ushort* __restrict__ Wob) {
    const int total = 2 * N4H + 4 * N4W;
    for (int i = blockIdx.x * blockDim.x + threadIdx.x; i < total; i += gridDim.x * blockDim.x) {
        if (i < N4H) {
            float4 v = reinterpret_cast<const float4*>(hidden)[i];
            ushort4 o = {f2b(v.x), f2b(v.y), f2b(v.z), f2b(v.w)};
            reinterpret_cast<ushort4*>(Hb)[i] = o;
        } else if (i < 2 * N4H) {
            int j = i - N4H;
            reinterpret_cast<float4*>(out)[j] = reinterpret_cast<const float4*>(bo)[j % (HID_ / 4)];
        } else {
            int local = i - 2 * N4H;
            int which = local / N4W, j = local - which * N4W;
            const float* src = which == 0 ? Wk : (which == 1 ? Wv : (which == 2 ? Wq : Wo));
            ushort* dst = which == 0 ? Wkb : (which == 1 ? Wvb : (which == 2 ? Wqb : Wob));
            float sc = (which == 2) ? 0.125f : 1.0f;   // fold 1/sqrt(HD) into Wq
            float4 v = reinterpret_cast<const float4*>(src)[j];
            ushort4 o = {f2b(v.x * sc), f2b(v.y * sc), f2b(v.z * sc), f2b(v.w * sc)};
            reinterpret_cast<ushort4*>(dst)[j] = o;
        }
    }
}

// ---------------- gather selected hidden rows (fp32 -> bf16, padded) -------
__global__ void gather_qb_kernel(const float* __restrict__ hidden, const int* __restrict__ idx,
                                 ushort* __restrict__ Qinb, int nq, int nqpad) {
    int m = blockIdx.x;                  // 0 .. B*nqpad-1
    int b = m / nqpad, qi = m - b * nqpad;
    int t = threadIdx.x;                 // 96 threads, 8 floats each
    ushort4* dst = reinterpret_cast<ushort4*>(Qinb + (size_t)m * HID_);
    if (qi < nq) {
        int srow = b * S_ + idx[qi];
        const float4* src = reinterpret_cast<const float4*>(hidden + (size_t)srow * HID_);
        float4 a = src[t * 2], c = src[t * 2 + 1];
        ushort4 o0 = {f2b(a.x), f2b(a.y), f2b(a.z), f2b(a.w)};
        ushort4 o1 = {f2b(c.x), f2b(c.y), f2b(c.z), f2b(c.w)};
        dst[t * 2] = o0;
        dst[t * 2 + 1] = o1;
    } else {
        ushort4 z = {0, 0, 0, 0};
        dst[t * 2] = z;
        dst[t * 2 + 1] = z;
    }
}

// ---------------- fused K+V projection GEMM --------------------------------
// grid (B*S/128, 12): y<6 -> K (KV layout), y>=6 -> V stored DIRECTLY in
// Vt layout [bh][d][s] (r-packed ushort4, s-contiguous).
__launch_bounds__(256)
__global__ void gemm_kv_kernel(const ushort* __restrict__ A,
                               const ushort* __restrict__ Wkb, const ushort* __restrict__ Wvb,
                               const float* __restrict__ bk, const float* __restrict__ bv,
                               ushort* __restrict__ Kb, ushort* __restrict__ Vt) {
    __shared__ __align__(16) ushort As[128 * 64];
    __shared__ __align__(16) ushort Ws[128 * 64];
    const int t = threadIdx.x;
    const int lane = t & 63, w = t >> 6;
    const int wr = w >> 1, wc = w & 1;
    const int m0 = blockIdx.x * 128;
    const bool isV = blockIdx.y >= 6;
    const int n0 = (isV ? (blockIdx.y - 6) : blockIdx.y) * 128;
    const ushort* W = isV ? Wvb : Wkb;
    const float* bias = isV ? bv : bk;

    f32x4 acc[4][4];
    #pragma unroll
    for (int i = 0; i < 4; ++i)
        #pragma unroll
        for (int j = 0; j < 4; ++j) acc[i][j] = (f32x4){0.f, 0.f, 0.f, 0.f};

    for (int k0 = 0; k0 < HID_; k0 += 64) {
        __syncthreads();
        #pragma unroll
        for (int it = 0; it < 4; ++it) {
            int sid = t + it * 256;
            int row = sid >> 3, seg = sid & 7;
            int cb = (seg * 16) ^ ((row & 7) << 4);
            glds16(A + (size_t)(m0 + row) * HID_ + k0 + cb / 2, (ushort*)((char*)As + sid * 16));
            glds16(W + (size_t)(n0 + row) * HID_ + k0 + cb / 2, (ushort*)((char*)Ws + sid * 16));
        }
        __syncthreads();

        short8 af[4][2], bf_[4][2];
        #pragma unroll
        for (int mi = 0; mi < 4; ++mi)
            #pragma unroll
            for (int kh = 0; kh < 2; ++kh)
                af[mi][kh] = *reinterpret_cast<const short8*>(
                    (char*)As + swzb(wr * 64 + mi * 16 + (lane & 15), (lane >> 4) * 16 + kh * 64, 128));
        #pragma unroll
        for (int ni = 0; ni < 4; ++ni)
            #pragma unroll
            for (int kh = 0; kh < 2; ++kh)
                bf_[ni][kh] = *reinterpret_cast<const short8*>(
                    (char*)Ws + swzb(wc * 64 + ni * 16 + (lane & 15), (lane >> 4) * 16 + kh * 64, 128));

        #pragma unroll
        for (int mi = 0; mi < 4; ++mi)
            #pragma unroll
            for (int ni = 0; ni < 4; ++ni) {
                acc[mi][ni] = __builtin_amdgcn_mfma_f32_16x16x32_bf16(af[mi][0], bf_[ni][0], acc[mi][ni], 0, 0, 0);
                acc[mi][ni] = __builtin_amdgcn_mfma_f32_16x16x32_bf16(af[mi][1], bf_[ni][1], acc[mi][ni], 0, 0, 0);
            }
    }

    float bl[4];
    #pragma unroll
    for (int ni = 0; ni < 4; ++ni)
        bl[ni] = bias[n0 + wc * 64 + ni * 16 + (lane & 15)];

    #pragma unroll
    for (int mi = 0; mi < 4; ++mi) {
        #pragma unroll
        for (int ni = 0; ni < 4; ++ni) {
            int n = n0 + wc * 64 + ni * 16 + (lane & 15);
            int h = n >> 6, d = n & 63;
            int s0 = m0 + wr * 64 + mi * 16 + (lane >> 4) * 4;   // 4 consecutive s (r=0..3)
            if (isV) {
                int b = s0 >> 13, s = s0 & (S_ - 1);
                ushort4 o = {f2b(acc[mi][ni][0] + bl[ni]), f2b(acc[mi][ni][1] + bl[ni]),
                             f2b(acc[mi][ni][2] + bl[ni]), f2b(acc[mi][ni][3] + bl[ni])};
                *reinterpret_cast<ushort4*>(&Vt[((size_t)(b * NH_ + h) * HD_ + d) * S_ + s]) = o;
            } else {
                #pragma unroll
                for (int r = 0; r < 4; ++r) {
                    int m = s0 + r;
                    int b = m >> 13, s = m & (S_ - 1);
                    Kb[(((size_t)(b * NH_ + h)) * S_ + s) * HD_ + d] = f2b(acc[mi][ni][r] + bl[ni]);
                }
            }
        }
    }
}

// ---------------- bf16 MFMA GEMM (Q and O projections) ---------------------
enum { GST_PLAIN = 1, GST_SCATF32 = 2 };

template<int MODE>
__launch_bounds__(256)
__global__ void gemm_bf16_kernel(const ushort* __restrict__ A, const ushort* __restrict__ W,
                                 const float* __restrict__ bias, float bscale,
                                 ushort* __restrict__ C, float* __restrict__ Cf,
                                 const int* __restrict__ idx, int nq, int Mq) {
    __shared__ __align__(16) ushort As[128 * 64];
    __shared__ __align__(16) ushort Ws[128 * 64];
    const int t = threadIdx.x;
    const int lane = t & 63, w = t >> 6;
    const int wr = w >> 1, wc = w & 1;
    const int m0 = blockIdx.x * 128;
    const int n0 = blockIdx.y * 128;

    f32x4 acc[4][4];
    #pragma unroll
    for (int i = 0; i < 4; ++i)
        #pragma unroll
        for (int j = 0; j < 4; ++j) acc[i][j] = (f32x4){0.f, 0.f, 0.f, 0.f};

    for (int k0 = 0; k0 < HID_; k0 += 64) {
        __syncthreads();
        #pragma unroll
        for (int it = 0; it < 4; ++it) {
            int sid = t + it * 256;
            int row = sid >> 3, seg = sid & 7;
            int cb = (seg * 16) ^ ((row & 7) << 4);
            glds16(A + (size_t)(m0 + row) * HID_ + k0 + cb / 2, (ushort*)((char*)As + sid * 16));
            glds16(W + (size_t)(n0 + row) * HID_ + k0 + cb / 2, (ushort*)((char*)Ws + sid * 16));
        }
        __syncthreads();

        short8 af[4][2], bf_[4][2];
        #pragma unroll
        for (int mi = 0; mi < 4; ++mi)
            #pragma unroll
            for (int kh = 0; kh < 2; ++kh)
                af[mi][kh] = *reinterpret_cast<const short8*>(
                    (char*)As + swzb(wr * 64 + mi * 16 + (lane & 15), (lane >> 4) * 16 + kh * 64, 128));
        #pragma unroll
        for (int ni = 0; ni < 4; ++ni)
            #pragma unroll
            for (int kh = 0; kh < 2; ++kh)
                bf_[ni][kh] = *reinterpret_cast<const short8*>(
                    (char*)Ws + swzb(wc * 64 + ni * 16 + (lane & 15), (lane >> 4) * 16 + kh * 64, 128));

        #pragma unroll
        for (int mi = 0; mi < 4; ++mi)
            #pragma unroll
            for (int ni = 0; ni < 4; ++ni) {
                acc[mi][ni] = __builtin_amdgcn_mfma_f32_16x16x32_bf16(af[mi][0], bf_[ni][0], acc[mi][ni], 0, 0, 0);
                acc[mi][ni] = __builtin_amdgcn_mfma_f32_16x16x32_bf16(af[mi][1], bf_[ni][1], acc[mi][ni], 0, 0, 0);
            }
    }

    float bl[4];
    #pragma unroll
    for (int ni = 0; ni < 4; ++ni)
        bl[ni] = bias[n0 + wc * 64 + ni * 16 + (lane & 15)] * bscale;

    #pragma unroll
    for (int mi = 0; mi < 4; ++mi) {
        #pragma unroll
        for (int ni = 0; ni < 4; ++ni) {
            int n = n0 + wc * 64 + ni * 16 + (lane & 15);
            #pragma unroll
            for (int r = 0; r < 4; ++r) {
                int m = m0 + wr * 64 + mi * 16 + (lane >> 4) * 4 + r;
                float fv = acc[mi][ni][r] + bl[ni];
                if (MODE == GST_PLAIN) {
                    C[(size_t)m * HID_ + n] = f2b(fv);
                } else {   // GST_SCATF32
                    if (m < Mq) {
                        int b = m / nq, qi = m - b * nq;
                        int srow = b * S_ + idx[qi];
                        Cf[(size_t)srow * HID_ + n] = fv;
                    }
                }
            }
        }
    }
}

// ---------------- pass1: QK^T via MFMA, partial (m,l) ----------------------
// 1-D grid of NC1*B*NH = 768 blocks (3 exact rounds on 256 CUs), 512 thr.
// Block stages its K chunk once; loops ALL q-tiles over it.
__launch_bounds__(512)
__global__ void attn_pass1_mfma(const ushort* __restrict__ Qsel, const ushort* __restrict__ Kb,
                                float2* __restrict__ mlp, int nq, int nqpad) {
    __shared__ __align__(16) ushort Ks[128 * 64];
    const int t = threadIdx.x;
    const int lane = t & 63, w = t >> 6;
    const int lin = blockIdx.x;
    const int chunk = lin & (NC1 - 1), bh = lin >> 5;
    const int b = bh / NH_, h = bh - b * NH_;
    const int nqt = nqpad >> 7;           // #128-row q-tiles (<=4)

    short8 qa[4][2];
    #pragma unroll
    for (int qt = 0; qt < 4; ++qt) {
        if (qt < nqt) {
            const ushort* qp = Qsel + (size_t)(b * nqpad + qt * 128 + 16 * w + (lane & 15)) * HID_
                               + h * HD_ + (lane >> 4) * 8;
            qa[qt][0] = *reinterpret_cast<const short8*>(qp);
            qa[qt][1] = *reinterpret_cast<const short8*>(qp + 32);
        }
    }

    float m_r[4][4], l_r[4][4];
    #pragma unroll
    for (int qt = 0; qt < 4; ++qt)
        #pragma unroll
        for (int r = 0; r < 4; ++r) { m_r[qt][r] = -1e30f; l_r[qt][r] = 0.f; }

    const ushort* kbase = Kb + (size_t)bh * S_ * HD_;

    for (int kb = 0; kb < KC1; kb += 128) {
        int k0 = chunk * KC1 + kb;
        __syncthreads();
        #pragma unroll
        for (int it = 0; it < 2; ++it) {
            int sid = t + it * 512;
            int row = sid >> 3, seg = sid & 7;
            int cb = (seg * 16) ^ ((row & 7) << 4);
            glds16(kbase + (size_t)(k0 + row) * HD_ + cb / 2, (ushort*)((char*)Ks + sid * 16));
        }
        __syncthreads();

        short8 kf[8][2];
        #pragma unroll
        for (int ns = 0; ns < 8; ++ns) {
            kf[ns][0] = *reinterpret_cast<const short8*>((char*)Ks + swzb(ns * 16 + (lane & 15), (lane >> 4) * 16, 128));
            kf[ns][1] = *reinterpret_cast<const short8*>((char*)Ks + swzb(ns * 16 + (lane & 15), (lane >> 4) * 16 + 64, 128));
        }

        #pragma unroll
        for (int qt = 0; qt < 4; ++qt) {
            if (qt >= nqt) continue;
            f32x4 sf[8];
            __builtin_amdgcn_s_setprio(1);
            #pragma unroll
            for (int ns = 0; ns < 8; ++ns) {
                f32x4 acc = {0.f, 0.f, 0.f, 0.f};
                acc = __builtin_amdgcn_mfma_f32_16x16x32_bf16(qa[qt][0], kf[ns][0], acc, 0, 0, 0);
                acc = __builtin_amdgcn_mfma_f32_16x16x32_bf16(qa[qt][1], kf[ns][1], acc, 0, 0, 0);
                sf[ns] = acc;
            }
            __builtin_amdgcn_s_setprio(0);
            #pragma unroll
            for (int r = 0; r < 4; ++r) {
                float bm = sf[0][r];
                #pragma unroll
                for (int ns = 1; ns < 8; ++ns) bm = fmaxf(bm, sf[ns][r]);
                float mn = fmaxf(m_r[qt][r], bm);
                float sum = 0.f;
                #pragma unroll
                for (int ns = 0; ns < 8; ++ns) sum += __expf(sf[ns][r] - mn);
                l_r[qt][r] = l_r[qt][r] * __expf(m_r[qt][r] - mn) + sum;
                m_r[qt][r] = mn;
            }
        }
    }

    #pragma unroll
    for (int qt = 0; qt < 4; ++qt) {
        if (qt >= nqt) continue;
        #pragma unroll
        for (int r = 0; r < 4; ++r) {
            float m = m_r[qt][r], l = l_r[qt][r];
            #pragma unroll
            for (int off = 1; off < 16; off <<= 1) {
                float om = __shfl_xor(m, off);
                float ol = __shfl_xor(l, off);
                float mn = fmaxf(m, om);
                l = l * __expf(m - mn) + ol * __expf(om - mn);
                m = mn;
            }
            if ((lane & 15) == 0) {
                int row = qt * 128 + 16 * w + 4 * (lane >> 4) + r;
                mlp[(size_t)chunk * (B_ * NH_ * nqpad) + (size_t)bh * nqpad + row] = make_float2(m, l);
            }
        }
    }
}

// ---------------- combine partial (m,l) ------------------------------------
__global__ void ml_reduce_kernel(const float2* __restrict__ mlp, float2* __restrict__ ml, int nqpad) {
    int i = blockIdx.x * blockDim.x + threadIdx.x;
    int total = B_ * NH_ * nqpad;
    if (i >= total) return;
    float m = -1e30f, l = 0.f;
    #pragma unroll
    for (int c = 0; c < NC1; ++c) {
        float2 v = mlp[(size_t)c * total + i];
        float mn = fmaxf(m, v.x);
        l = l * __expf(m - mn) + v.y * __expf(v.x - mn);
        m = mn;
    }
    ml[i] = make_float2(m, l);
}

// ---------------- pass2: recompute QK^T, write probs, PV -> ctx partial ----
// 1-D grid of 2*NC2*B*NH = 768 blocks, 512 thr. Each block: half the q-rows
// x one 512-key chunk. The two q-halves sharing a (chunk,bh) are placed on
// the SAME XCD (bijective decode) so the second K/V read L2-hits.
__launch_bounds__(512)
__global__ void attn_pass2_mfma(const ushort* __restrict__ Qsel, const ushort* __restrict__ Kb,
                                const ushort* __restrict__ Vtb, const float2* __restrict__ ml,
                                float* __restrict__ probs, float* __restrict__ ctxp, int nq, int nqpad) {
    __shared__ __align__(16) ushort Ks[128 * 64];
    __shared__ __align__(16) ushort Vs[64 * 128];
    __shared__ __align__(16) ushort Ps[128 * 128];
    __shared__ float mls[256], ils[256];
    const int t = threadIdx.x;
    const int lane = t & 63, w = t >> 6;
    // bijective XCD-pairing decode: 768 = 8 xcd * 96 slots
    const int lin = blockIdx.x;
    const int xcd = lin & 7, slot = lin >> 3;
    const int qhalf = slot & 1, pl = slot >> 1;
    const int pair = xcd * 48 + pl;            // 0..383 = chunk(16) x bh(24)
    const int chunk = pair & (NC2 - 1), bh = pair >> 4;
    const int b = bh / NH_, h = bh - b * NH_;
    const int nqt = nqpad >> 7;

    short8 qa[2][2];
    #pragma unroll
    for (int ql = 0; ql < 2; ++ql) {
        int qt = qhalf * 2 + ql;
        if (qt < nqt) {
            const ushort* qp = Qsel + (size_t)(b * nqpad + qt * 128 + 16 * w + (lane & 15)) * HID_
                               + h * HD_ + (lane >> 4) * 8;
            qa[ql][0] = *reinterpret_cast<const short8*>(qp);
            qa[ql][1] = *reinterpret_cast<const short8*>(qp + 32);
        }
    }

    if (t < 256) {
        int row = qhalf * 256 + t;
        if (row < nqpad) {
            float2 v = ml[(size_t)bh * nqpad + row];
            mls[t] = v.x;
            ils[t] = 1.f / v.y;
        }
    }

    const ushort* kbase  = Kb  + (size_t)bh * S_ * HD_;
    const ushort* vtbase = Vtb + (size_t)bh * HD_ * S_;
    const size_t prow0 = (size_t)bh * nq;

    f32x4 accc[2][4];
    #pragma unroll
    for (int ql = 0; ql < 2; ++ql)
        #pragma unroll
        for (int d = 0; d < 4; ++d) accc[ql][d] = (f32x4){0.f, 0.f, 0.f, 0.f};

    for (int kb = 0; kb < KC2; kb += 128) {
        int k0 = chunk * KC2 + kb;
        __syncthreads();
        #pragma unroll
        for (int it = 0; it < 2; ++it) {   // K tile: 128 keys x 128B
            int sid = t + it * 512;
            int row = sid >> 3, seg = sid & 7;
            int cb = (seg * 16) ^ ((row & 7) << 4);
            glds16(kbase + (size_t)(k0 + row) * HD_ + cb / 2, (ushort*)((char*)Ks + sid * 16));
        }
        #pragma unroll
        for (int it = 0; it < 2; ++it) {   // Vt tile: 64 d-rows x 256B
            int sid = t + it * 512;
            int row = sid >> 4, seg = sid & 15;
            int cb = (seg * 16) ^ ((row & 7) << 4);
            glds16(vtbase + (size_t)row * S_ + k0 + cb / 2, (ushort*)((char*)Vs + sid * 16));
        }
        __syncthreads();

        #pragma unroll
        for (int ql = 0; ql < 2; ++ql) {
            int qt = qhalf * 2 + ql;
            if (qt >= nqt) continue;
            float mrq[4], ilq[4];
            #pragma unroll
            for (int r = 0; r < 4; ++r) {
                int lrow = ql * 128 + 16 * w + 4 * (lane >> 4) + r;
                mrq[r] = mls[lrow];
                ilq[r] = ils[lrow];
            }
            __builtin_amdgcn_s_setprio(1);
            #pragma unroll
            for (int ns = 0; ns < 8; ++ns) {
                short8 b0 = *reinterpret_cast<const short8*>((char*)Ks + swzb(ns * 16 + (lane & 15), (lane >> 4) * 16, 128));
                short8 b1 = *reinterpret_cast<const short8*>((char*)Ks + swzb(ns * 16 + (lane & 15), (lane >> 4) * 16 + 64, 128));
                f32x4 acc = {0.f, 0.f, 0.f, 0.f};
                acc = __builtin_amdgcn_mfma_f32_16x16x32_bf16(qa[ql][0], b0, acc, 0, 0, 0);
                acc = __builtin_amdgcn_mfma_f32_16x16x32_bf16(qa[ql][1], b1, acc, 0, 0, 0);
                #pragma unroll
                for (int r = 0; r < 4; ++r) {
                    int rl = 16 * w + 4 * (lane >> 4) + r;
                    float p = __expf(acc[r] - mrq[r]) * ilq[r];
                    int qrow = qt * 128 + rl;
                    if (qrow < nq)
                        probs[(prow0 + qrow) * (size_t)S_ + k0 + ns * 16 + (lane & 15)] = p;
                    *reinterpret_cast<ushort*>((char*)Ps + swzb(rl, (ns * 16 + (lane & 15)) * 2, 256)) = f2b(p);
                }
            }
            // PV: wave-local P slice, no barrier needed
            short8 pa[4];
            #pragma unroll
            for (int ks = 0; ks < 4; ++ks)
                pa[ks] = *reinterpret_cast<const short8*>((char*)Ps + swzb(16 * w + (lane & 15), ks * 64 + (lane >> 4) * 16, 256));
            #pragma unroll
            for (int ds = 0; ds < 4; ++ds) {
                #pragma unroll
                for (int ks = 0; ks < 4; ++ks) {
                    short8 vb = *reinterpret_cast<const short8*>((char*)Vs + swzb(ds * 16 + (lane & 15), ks * 64 + (lane >> 4) * 16, 256));
                    accc[ql][ds] = __builtin_amdgcn_mfma_f32_16x16x32_bf16(pa[ks], vb, accc[ql][ds], 0, 0, 0);
                }
            }
            __builtin_amdgcn_s_setprio(0);
        }
    }

    // store ctx partial for this chunk
    float* dst = ctxp + (size_t)chunk * ((size_t)B_ * nq * HID_);
    #pragma unroll
    for (int ql = 0; ql < 2; ++ql) {
        int qt = qhalf * 2 + ql;
        if (qt >= nqt) continue;
        #pragma unroll
        for (int ds = 0; ds < 4; ++ds) {
            #pragma unroll
            for (int r = 0; r < 4; ++r) {
                int qrow = qt * 128 + 16 * w + 4 * (lane >> 4) + r;
                if (qrow < nq)
                    dst[(size_t)(b * nq + qrow) * HID_ + h * HD_ + ds * 16 + (lane & 15)] = accc[ql][ds][r];
            }
        }
    }
}

// ---------------- sum partial ctx over NC2 chunks, emit bf16 ---------------
__global__ void ctx_reduce_kernel(const float* __restrict__ ctxp, ushort* __restrict__ ctxb, int Mq) {
    const int n4 = Mq * (HID_ / 4);
    const float4* src = reinterpret_cast<const float4*>(ctxp);
    ushort4* dst = reinterpret_cast<ushort4*>(ctxb);
    for (int i = blockIdx.x * blockDim.x + threadIdx.x; i < n4; i += gridDim.x * blockDim.x) {
        float4 s = make_float4(0.f, 0.f, 0.f, 0.f);
        #pragma unroll
        for (int c = 0; c < NC2; ++c) {
            float4 v = src[(size_t)c * n4 + i];
            s.x += v.x; s.y += v.y; s.z += v.z; s.w += v.w;
        }
        ushort4 o;
        o.x = f2b(s.x); o.y = f2b(s.y); o.z = f2b(s.z); o.w = f2b(s.w);
        dst[i] = o;
    }
}

// ---------------------------------------------------------------------------
extern "C" void kernel_launch(void* const* d_in, const int* in_sizes, int n_in,
                              void* d_out, int out_size, void* d_ws, size_t ws_size,
                              hipStream_t stream) {
    const float* hidden = (const float*)d_in[0];
    const int*   idx    = (const int*)d_in[1];
    const float* Wq = (const float*)d_in[2];
    const float* bq = (const float*)d_in[3];
    const float* Wk = (const float*)d_in[4];
    const float* bk = (const float*)d_in[5];
    const float* Wv = (const float*)d_in[6];
    const float* bv = (const float*)d_in[7];
    const float* Wo = (const float*)d_in[8];
    const float* bo = (const float*)d_in[9];
    const int nq = in_sizes[1];
    const int qt128 = (nq + 127) / 128;
    const int nqpad = qt128 * 128;       // 512 for this problem
    const int Mq = B_ * nq;
    const int Mqp = B_ * nqpad;

    float* out   = (float*)d_out;
    float* probs = out + (size_t)B_ * S_ * HID_;

    char* ws = (char*)d_ws;
    const size_t kvN = (size_t)B_ * NH_ * S_ * HD_;   // 12.58M elems
    ushort* Hb    = (ushort*)ws;                 ws += kvN * 2;
    ushort* K_buf = (ushort*)ws;                 ws += kvN * 2;
    ushort* Vt    = (ushort*)ws;                 ws += kvN * 2;
    ushort* Wkb   = (ushort*)ws;                 ws += (size_t)HID_ * HID_ * 2;
    ushort* Wvb   = (ushort*)ws;                 ws += (size_t)HID_ * HID_ * 2;
    ushort* Wqb   = (ushort*)ws;                 ws += (size_t)HID_ * HID_ * 2;
    ushort* Wob   = (ushort*)ws;                 ws += (size_t)HID_ * HID_ * 2;
    ushort* Qinb  = (ushort*)ws;                 ws += (size_t)Mqp * HID_ * 2;
    ushort* Qsel  = (ushort*)ws;                 ws += (size_t)Mqp * HID_ * 2;
    ushort* ctxb  = (ushort*)ws;                 ws += (size_t)Mqp * HID_ * 2;
    float*  ctxp  = (float*)ws;                  ws += (size_t)NC2 * Mq * HID_ * 4;
    float2* mlp   = (float2*)ws;                 ws += (size_t)NC1 * B_ * NH_ * nqpad * 8;
    float2* ml    = (float2*)ws;                 ws += (size_t)B_ * NH_ * nqpad * 8;

    // prep: hidden->bf16, out bias-fill, weights->bf16
    prep_kernel<<<2048, 256, 0, stream>>>(hidden, bo, Wk, Wv, Wq, Wo,
                                          Hb, out, Wkb, Wvb, Wqb, Wob);
    gather_qb_kernel<<<Mqp, 96, 0, stream>>>(hidden, idx, Qinb, nq, nqpad);

    // fused K+V projection (V stored directly transposed)
    dim3 gKV(B_ * S_ / 128, 12);
    gemm_kv_kernel<<<gKV, 256, 0, stream>>>(Hb, Wkb, Wvb, bk, bv, K_buf, Vt);

    dim3 gQ(Mqp / 128, HID_ / 128);
    gemm_bf16_kernel<GST_PLAIN><<<gQ, 256, 0, stream>>>(Qinb, Wqb, bq, 0.125f, Qsel, nullptr, nullptr, 0, 0);

    // attention
    attn_pass1_mfma<<<NC1 * B_ * NH_, 512, 0, stream>>>(Qsel, K_buf, mlp, nq, nqpad);

    int totalml = B_ * NH_ * nqpad;
    ml_reduce_kernel<<<(totalml + 255) / 256, 256, 0, stream>>>(mlp, ml, nqpad);

    attn_pass2_mfma<<<2 * NC2 * B_ * NH_, 512, 0, stream>>>(Qsel, K_buf, Vt, ml, probs, ctxp, nq, nqpad);

    ctx_reduce_kernel<<<1024, 256, 0, stream>>>(ctxp, ctxb, Mq);

    // O projection: bf16 MFMA, scatter fp32 rows into out
    gemm_bf16_kernel<GST_SCATF32><<<gQ, 256, 0, stream>>>(ctxb, Wob, bo, 1.0f, nullptr, out, idx, nq, Mq);
}